// Round 15
// baseline (1625.282 us; speedup 1.0000x reference)
//
#include <hip/hip_runtime.h>
#include <hip/hip_bf16.h>

#define DIM 2048
#define BM 128
#define BN 256
#define BK 64
#define KSTEPS (DIM / BK)          // 32 K-tiles
#define A_TILE_BYTES (BM * BK)     // 8192 B
#define B_TILE_BYTES (BN * BK)     // 16384 B
#define NLEV 8                     // global top-8 cascade

typedef _Float16 f16x8 __attribute__((ext_vector_type(8)));
typedef float f32x4 __attribute__((ext_vector_type(4)));
typedef int i32x4 __attribute__((ext_vector_type(4)));
typedef unsigned long long u64;

#define INV_SX 27.6f               // X scale: clip at 4.60 sigma
#define INV_SVN 1150.0f            // normalized-V scale: clip at |vn|=0.1104

typedef const unsigned int __attribute__((address_space(1))) gu32;
typedef unsigned int __attribute__((address_space(3))) lu32;

__device__ __forceinline__ void gl_lds16(const void* g, void* l) {
    __builtin_amdgcn_global_load_lds((gu32*)g, (lu32*)l, 16, 0, 0);
}

// Monotone float->uint map; pack (val, col) so u64 max = (max val, first col on ties)
__device__ __forceinline__ u64 pack_key(float v, unsigned int col) {
    unsigned int b = __float_as_uint(v);
    b ^= (unsigned int)(((int)b >> 31)) | 0x80000000u;
    return ((u64)b << 32) | (u64)(~col);
}
// integer-dot key: monotone in dot, lowest col on ties
__device__ __forceinline__ u64 pack_key_i(int dot, unsigned int col) {
    unsigned int b = (unsigned int)dot ^ 0x80000000u;
    return ((u64)b << 32) | (u64)(~col);
}
__device__ __forceinline__ u64 umax64(u64 a, u64 b) { return a > b ? a : b; }
__device__ __forceinline__ u64 umin64(u64 a, u64 b) { return a < b ? a : b; }

// lock-free exact top-N cascade (order-independent => deterministic).
__device__ __forceinline__ void cascadeN(u64* Rrow, int stride, u64 k) {
    if (k <= Rrow[(NLEV - 1) * stride]) return;   // monotone prune (safe)
#pragma unroll
    for (int l = 0; l < NLEV; ++l) {
        u64 old = atomicMax(&Rrow[l * stride], k);
        k = umin64(k, old);
        if (!k) return;
    }
}
__device__ __forceinline__ void cascade3(u64* r1, u64* r2, u64* r3, u64 k) {
    u64 old = atomicMax(r1, k);
    k = umin64(k, old);
    if (k) {
        old = atomicMax(r2, k);
        k = umin64(k, old);
        if (k) atomicMax(r3, k);
    }
}

// tile image: 128B lines (row pairs of 64B), 8x16B slots, slot ^= line&7
// (byte-identical to the r6-r14 verified image)
__device__ __forceinline__ int toff(int row, int kg) {
    const int line = row >> 1;
    const int s8 = ((row & 1) << 2) | kg;
    return line * 128 + ((s8 ^ (line & 7)) << 4);   // byte offset
}

// old f16 swizzle (used by the 128^2 fallback kernel only)
__device__ __forceinline__ int swz(int row, int slot) {
    return row * 32 + (slot ^ ((row >> 1) & 3)) * 8;
}

__global__ void vocab_invnorm_kernel(const float* __restrict__ Vg,
                                     float* __restrict__ invnorm) {
    const int v = blockIdx.x;
    const int t = threadIdx.x;
    const float* row = Vg + (size_t)v * DIM;
    float4 f0 = *reinterpret_cast<const float4*>(row + t * 8);
    float4 f1 = *reinterpret_cast<const float4*>(row + t * 8 + 4);
    float s = f0.x*f0.x + f0.y*f0.y + f0.z*f0.z + f0.w*f0.w
            + f1.x*f1.x + f1.y*f1.y + f1.z*f1.z + f1.w*f1.w;
#pragma unroll
    for (int off = 32; off > 0; off >>= 1) s += __shfl_down(s, off);
    __shared__ float ls[4];
    const int lane = t & 63, w = t >> 6;
    if (lane == 0) ls[w] = s;
    __syncthreads();
    if (t == 0) {
        float tot = ls[0] + ls[1] + ls[2] + ls[3];
        invnorm[v] = 1.0f / fmaxf(sqrtf(tot), 1e-12f);
    }
}

__device__ __forceinline__ void q16pack(const float* xv, float s, int* out4) {
#pragma unroll
    for (int g = 0; g < 4; ++g) {
        int p = 0;
#pragma unroll
        for (int e = 0; e < 4; ++e) {
            int q = __float2int_rn(xv[g * 4 + e] * s);
            q = q > 127 ? 127 : (q < -127 ? -127 : q);
            p |= (q & 255) << (e * 8);
        }
        out4[g] = p;
    }
}

// X -> tiled i8, [128][64] tiles in the line/slot-swizzled image (fixed scale)
__global__ void convert_x_q(const float* __restrict__ X, signed char* __restrict__ Xq) {
    const int tile = blockIdx.x;          // mblk*32 + ks
    const int mblk = tile >> 5, ks = tile & 31;
    const float* src = X + (size_t)(mblk * BM) * DIM + ks * BK;
    signed char* dst = Xq + (size_t)tile * A_TILE_BYTES;
    const int t = threadIdx.x;
#pragma unroll
    for (int u = 0; u < 2; ++u) {
        const int c = t + u * 256;        // 0..511 chunk id (16 B each)
        const int line = c >> 3;
        const int s8 = (c & 7) ^ (line & 7);
        const int row = (line << 1) | (s8 >> 2);
        const int cs = s8 & 3;            // 16-elem slot
        const float* s = src + (size_t)row * DIM + cs * 16;
        float xv[16];
        *(float4*)(&xv[0])  = *(const float4*)(s);
        *(float4*)(&xv[4])  = *(const float4*)(s + 4);
        *(float4*)(&xv[8])  = *(const float4*)(s + 8);
        *(float4*)(&xv[12]) = *(const float4*)(s + 12);
        int q4[4];
        q16pack(xv, INV_SX, q4);
        *(int4*)(dst + c * 16) = make_int4(q4[0], q4[1], q4[2], q4[3]);
    }
}

// V -> tiled i8, [256][64] tiles (same image), normalized then fixed-scale
__global__ void convert_v_q(const float* __restrict__ Vg,
                            const float* __restrict__ invnorm,
                            signed char* __restrict__ Vq) {
    const int tile = blockIdx.x;          // nblk*32 + ks
    const int nblk = tile >> 5, ks = tile & 31;
    const float* src = Vg + (size_t)(nblk * BN) * DIM + ks * BK;
    signed char* dst = Vq + (size_t)tile * B_TILE_BYTES;
    const int t = threadIdx.x;
#pragma unroll
    for (int u = 0; u < 4; ++u) {
        const int c = t + u * 256;        // 0..1023
        const int line = c >> 3;
        const int s8 = (c & 7) ^ (line & 7);
        const int row = (line << 1) | (s8 >> 2);
        const int cs = s8 & 3;
        const float sc = invnorm[nblk * BN + row] * INV_SVN;
        const float* s = src + (size_t)row * DIM + cs * 16;
        float xv[16];
        *(float4*)(&xv[0])  = *(const float4*)(s);
        *(float4*)(&xv[4])  = *(const float4*)(s + 4);
        *(float4*)(&xv[8])  = *(const float4*)(s + 8);
        *(float4*)(&xv[12]) = *(const float4*)(s + 12);
        int q4[4];
        q16pack(xv, sc, q4);
        *(int4*)(dst + c * 16) = make_int4(q4[0], q4[1], q4[2], q4[3]);
    }
}

#define LOAD8(ar, br, ap, bp)                                   \
    ar##0 = *(const i32x4*)((ap) + offA[0]);                    \
    ar##1 = *(const i32x4*)((ap) + offA[1]);                    \
    ar##2 = *(const i32x4*)((ap) + offA[2]);                    \
    ar##3 = *(const i32x4*)((ap) + offA[3]);                    \
    br##0 = *(const i32x4*)((bp) + offB[0]);                    \
    br##1 = *(const i32x4*)((bp) + offB[1]);                    \
    br##2 = *(const i32x4*)((bp) + offB[2]);                    \
    br##3 = *(const i32x4*)((bp) + offB[3]);

#define MFMA16I(ar, br)                                                              \
    acc[0][0] = __builtin_amdgcn_mfma_i32_16x16x64_i8(ar##0, br##0, acc[0][0], 0, 0, 0); \
    acc[0][1] = __builtin_amdgcn_mfma_i32_16x16x64_i8(ar##0, br##1, acc[0][1], 0, 0, 0); \
    acc[0][2] = __builtin_amdgcn_mfma_i32_16x16x64_i8(ar##0, br##2, acc[0][2], 0, 0, 0); \
    acc[0][3] = __builtin_amdgcn_mfma_i32_16x16x64_i8(ar##0, br##3, acc[0][3], 0, 0, 0); \
    acc[1][0] = __builtin_amdgcn_mfma_i32_16x16x64_i8(ar##1, br##0, acc[1][0], 0, 0, 0); \
    acc[1][1] = __builtin_amdgcn_mfma_i32_16x16x64_i8(ar##1, br##1, acc[1][1], 0, 0, 0); \
    acc[1][2] = __builtin_amdgcn_mfma_i32_16x16x64_i8(ar##1, br##2, acc[1][2], 0, 0, 0); \
    acc[1][3] = __builtin_amdgcn_mfma_i32_16x16x64_i8(ar##1, br##3, acc[1][3], 0, 0, 0); \
    acc[2][0] = __builtin_amdgcn_mfma_i32_16x16x64_i8(ar##2, br##0, acc[2][0], 0, 0, 0); \
    acc[2][1] = __builtin_amdgcn_mfma_i32_16x16x64_i8(ar##2, br##1, acc[2][1], 0, 0, 0); \
    acc[2][2] = __builtin_amdgcn_mfma_i32_16x16x64_i8(ar##2, br##2, acc[2][2], 0, 0, 0); \
    acc[2][3] = __builtin_amdgcn_mfma_i32_16x16x64_i8(ar##2, br##3, acc[2][3], 0, 0, 0); \
    acc[3][0] = __builtin_amdgcn_mfma_i32_16x16x64_i8(ar##3, br##0, acc[3][0], 0, 0, 0); \
    acc[3][1] = __builtin_amdgcn_mfma_i32_16x16x64_i8(ar##3, br##1, acc[3][1], 0, 0, 0); \
    acc[3][2] = __builtin_amdgcn_mfma_i32_16x16x64_i8(ar##3, br##2, acc[3][2], 0, 0, 0); \
    acc[3][3] = __builtin_amdgcn_mfma_i32_16x16x64_i8(ar##3, br##3, acc[3][3], 0, 0, 0);

// 512 threads = 8 waves (2m x 4n), wave tile 64x64, block tile 128x256.
// Zero LDS, zero barriers; explicit register DOUBLE-BUFFER (unroll-2):
// each iteration issues the NEXT tile's 8 fragment loads before MFMAing
// the current tile -> every load gets a full MFMA-cluster rotation
// (~1000 cy across the SIMD's waves) to cover L2/L3 latency.
__global__ __launch_bounds__(512) void sim_i8_pipe(
        const signed char* __restrict__ Xq, const signed char* __restrict__ Vq,
        u64* __restrict__ R, int M) {
    const int tid = threadIdx.x;
    // XCD-chunked bijective swizzle: 8000 blocks = 8 x 1000; m-fastest in chunk
    const int flat = blockIdx.x;
    const int idx  = (flat & 7) * 1000 + (flat >> 3);
    const int mblk = idx & 63;           // M/128 = 64
    const int nblk = idx >> 6;           // NV/256 = 125

    const int lane = tid & 63;
    const int w  = tid >> 6;             // 0..7
    const int wm = w >> 2, wn = w & 3;   // 2x4 wave grid; wave tile 64x64
    const int lr = lane & 15;
    const int kg = lane >> 4;

    const signed char* Atiles = Xq + (size_t)mblk * KSTEPS * A_TILE_BYTES;
    const signed char* Btiles = Vq + (size_t)nblk * KSTEPS * B_TILE_BYTES;

    i32x4 acc[4][4] = {};

    int offA[4], offB[4];
#pragma unroll
    for (int i = 0; i < 4; ++i) offA[i] = toff(wm * 64 + i * 16 + lr, kg);
#pragma unroll
    for (int j = 0; j < 4; ++j) offB[j] = toff(wn * 64 + j * 16 + lr, kg);

    i32x4 a0, a1, a2, a3, b0, b1, b2, b3;       // current tile
    i32x4 n0, n1, n2, n3, p0, p1, p2, p3;       // next tile (prefetch)

    // prologue: load tile 0
    LOAD8(a, b, Atiles, Btiles);

    for (int kt = 0; kt < KSTEPS; kt += 2) {
        // phase 1: prefetch tile kt+1, compute tile kt
        {
            const signed char* ap = Atiles + (size_t)(kt + 1) * A_TILE_BYTES;
            const signed char* bp = Btiles + (size_t)(kt + 1) * B_TILE_BYTES;
            LOAD8(n, p, ap, bp);
        }
        __builtin_amdgcn_s_setprio(1);
        MFMA16I(a, b);
        __builtin_amdgcn_s_setprio(0);
        // phase 2: prefetch tile kt+2, compute tile kt+1
        if (kt + 2 < KSTEPS) {
            const signed char* ap = Atiles + (size_t)(kt + 2) * A_TILE_BYTES;
            const signed char* bp = Btiles + (size_t)(kt + 2) * B_TILE_BYTES;
            LOAD8(a, b, ap, bp);
        }
        __builtin_amdgcn_s_setprio(1);
        MFMA16I(n, p);
        __builtin_amdgcn_s_setprio(0);
    }

    // epilogue: per-row top-2 within wave cols -> global top-8 cascade
    const int m0 = mblk * BM, nc0 = nblk * BN;
#pragma unroll
    for (int i = 0; i < 4; ++i) {
#pragma unroll
        for (int r = 0; r < 4; ++r) {
            u64 k[4];
#pragma unroll
            for (int j = 0; j < 4; ++j)
                k[j] = pack_key_i(acc[i][j][r],
                                  (unsigned int)(nc0 + wn * 64 + j * 16 + lr));
            u64 m01 = umax64(k[0], k[1]), q01 = umin64(k[0], k[1]);
            u64 m23 = umax64(k[2], k[3]), q23 = umin64(k[2], k[3]);
            u64 a1k = umax64(m01, m23);
            u64 a2k = umax64(umin64(m01, m23), umax64(q01, q23));
#pragma unroll
            for (int mask = 1; mask < 16; mask <<= 1) {
                u64 o1 = __shfl_xor(a1k, mask);
                u64 o2 = __shfl_xor(a2k, mask);
                u64 t1 = umax64(a1k, o1);
                a2k = umax64(umin64(a1k, o1), umax64(a2k, o2));
                a1k = t1;
            }
            if (lr == 0) {
                const int row = m0 + wm * 64 + i * 16 + kg * 4 + r;
                cascadeN(&R[row], M, a1k);
                cascadeN(&R[row], M, a2k);
            }
        }
    }
}

// ---------------- fallback (verified round-3 path, 128^2 f16; used if ws too small) ----------------
__global__ __launch_bounds__(256) void sim_coarse_fallback(
        const float* __restrict__ X, const float* __restrict__ Vg,
        const float* __restrict__ invnorm,
        u64* __restrict__ R1, u64* __restrict__ R2, u64* __restrict__ R3) {
    __shared__ alignas(16) _Float16 Ah[128 * 32];
    __shared__ alignas(16) _Float16 Bh[128 * 32];
    const int tid = threadIdx.x;
    const int flat = blockIdx.x;
    const int idx  = (flat & 7) * 2000 + (flat >> 3);
    const int panel = idx / 3200;
    const int w_    = idx - panel * 3200;
    const int mblk  = w_ & 63;
    const int nblk  = panel * 50 + (w_ >> 6);
    const int m0 = mblk * 128, n0 = nblk * 128;
    const int lane = tid & 63;
    const int w  = tid >> 6;
    const int wm = w >> 1, wn = w & 1;
    const int lr = lane & 15;
    const int kg = lane >> 4;
    const int sr  = tid >> 2;
    const int skc = tid & 3;
    const float* Aptr0 = X  + (size_t)(m0 + sr)      * DIM + skc * 8;
    const float* Aptr1 = X  + (size_t)(m0 + 64 + sr) * DIM + skc * 8;
    const float* Bptr0 = Vg + (size_t)(n0 + sr)      * DIM + skc * 8;
    const float* Bptr1 = Vg + (size_t)(n0 + 64 + sr) * DIM + skc * 8;
    float4 ra[4], rb[4];
    ra[0] = *(const float4*)(Aptr0);     ra[1] = *(const float4*)(Aptr0 + 4);
    ra[2] = *(const float4*)(Aptr1);     ra[3] = *(const float4*)(Aptr1 + 4);
    rb[0] = *(const float4*)(Bptr0);     rb[1] = *(const float4*)(Bptr0 + 4);
    rb[2] = *(const float4*)(Bptr1);     rb[3] = *(const float4*)(Bptr1 + 4);
    f32x4 acc[4][4] = {};
    const int wA0 = swz(sr, skc), wA1 = swz(sr + 64, skc);
    for (int ks = 0; ks < 64; ++ks) {
        {
            f16x8 h; float xv[8];
            *(float4*)(&xv[0]) = ra[0]; *(float4*)(&xv[4]) = ra[1];
#pragma unroll
            for (int e = 0; e < 8; ++e) h[e] = (_Float16)xv[e];
            *(f16x8*)(&Ah[wA0]) = h;
            *(float4*)(&xv[0]) = ra[2]; *(float4*)(&xv[4]) = ra[3];
#pragma unroll
            for (int e = 0; e < 8; ++e) h[e] = (_Float16)xv[e];
            *(f16x8*)(&Ah[wA1]) = h;
            *(float4*)(&xv[0]) = rb[0]; *(float4*)(&xv[4]) = rb[1];
#pragma unroll
            for (int e = 0; e < 8; ++e) h[e] = (_Float16)xv[e];
            *(f16x8*)(&Bh[wA0]) = h;
            *(float4*)(&xv[0]) = rb[2]; *(float4*)(&xv[4]) = rb[3];
#pragma unroll
            for (int e = 0; e < 8; ++e) h[e] = (_Float16)xv[e];
            *(f16x8*)(&Bh[wA1]) = h;
        }
        __syncthreads();
        if (ks + 1 < 64) {
            const int ko = (ks + 1) * 32;
            ra[0] = *(const float4*)(Aptr0 + ko); ra[1] = *(const float4*)(Aptr0 + ko + 4);
            ra[2] = *(const float4*)(Aptr1 + ko); ra[3] = *(const float4*)(Aptr1 + ko + 4);
            rb[0] = *(const float4*)(Bptr0 + ko); rb[1] = *(const float4*)(Bptr0 + ko + 4);
            rb[2] = *(const float4*)(Bptr1 + ko); rb[3] = *(const float4*)(Bptr1 + ko + 4);
        }
        f16x8 bhf[4];
#pragma unroll
        for (int j = 0; j < 4; ++j)
            bhf[j] = *(const f16x8*)(&Bh[swz(wn * 64 + j * 16 + lr, kg)]);
#pragma unroll
        for (int i = 0; i < 4; ++i) {
            f16x8 ahf = *(const f16x8*)(&Ah[swz(wm * 64 + i * 16 + lr, kg)]);
#pragma unroll
            for (int j = 0; j < 4; ++j)
                acc[i][j] = __builtin_amdgcn_mfma_f32_16x16x32_f16(ahf, bhf[j], acc[i][j], 0, 0, 0);
        }
        __syncthreads();
    }
    float inv[4];
#pragma unroll
    for (int j = 0; j < 4; ++j) inv[j] = invnorm[n0 + wn * 64 + j * 16 + lr];
#pragma unroll
    for (int i = 0; i < 4; ++i) {
#pragma unroll
        for (int r = 0; r < 4; ++r) {
            u64 k[4];
#pragma unroll
            for (int j = 0; j < 4; ++j)
                k[j] = pack_key(acc[i][j][r] * inv[j],
                                (unsigned int)(n0 + wn * 64 + j * 16 + lr));
            u64 m01 = umax64(k[0], k[1]), n01 = umin64(k[0], k[1]);
            u64 m23 = umax64(k[2], k[3]), n23 = umin64(k[2], k[3]);
            u64 a1 = umax64(m01, m23);
            u64 a2 = umax64(umin64(m01, m23), umax64(n01, n23));
#pragma unroll
            for (int mask = 1; mask < 16; mask <<= 1) {
                u64 b1 = __shfl_xor(a1, mask);
                u64 b2 = __shfl_xor(a2, mask);
                u64 t1 = umax64(a1, b1);
                a2 = umax64(umin64(a1, b1), umax64(a2, b2));
                a1 = t1;
            }
            if (lr == 0) {
                const int row = m0 + wm * 64 + i * 16 + kg * 4 + r;
                cascade3(&R1[row], &R2[row], &R3[row], a1);
                cascade3(&R1[row], &R2[row], &R3[row], a2);
            }
        }
    }
}

// block-wide sum reduction; returns total to ALL threads
__device__ __forceinline__ float block_sum(float v, float* sbuf, int t) {
#pragma unroll
    for (int off = 32; off > 0; off >>= 1) v += __shfl_down(v, off);
    const int lane = t & 63, w = t >> 6;
    __syncthreads();
    if (lane == 0) sbuf[w] = v;
    __syncthreads();
    return sbuf[0] + sbuf[1] + sbuf[2] + sbuf[3];
}

__global__ void rescue_finalize_kernel(const float* __restrict__ X,
                                       const float* __restrict__ Vg,
                                       const u64* __restrict__ R, int M, int NV,
                                       float* __restrict__ outx,
                                       float* __restrict__ outid) {
    const int row = blockIdx.x;
    const int t = threadIdx.x;
    __shared__ float sbuf[4];

    int cand[NLEV];
#pragma unroll
    for (int c = 0; c < NLEV; ++c) {
        unsigned int id = ~(unsigned int)(R[c * M + row] & 0xFFFFFFFFull);
        cand[c] = (id < (unsigned int)NV) ? (int)id : 0;
    }

    const float* x = X + (size_t)row * DIM;
    float4 x0 = *reinterpret_cast<const float4*>(x + t * 8);
    float4 x1 = *reinterpret_cast<const float4*>(x + t * 8 + 4);
    float xxp = x0.x*x0.x + x0.y*x0.y + x0.z*x0.z + x0.w*x0.w
              + x1.x*x1.x + x1.y*x1.y + x1.z*x1.z + x1.w*x1.w;
    const float xx = block_sum(xxp, sbuf, t);
    const float xn = fmaxf(sqrtf(xx), 1e-12f);

    u64 bestkey = 0ull;
    int bestid = cand[0];
    float bestsa = 0.f;
#pragma unroll
    for (int c = 0; c < NLEV; ++c) {
        const float* v = Vg + (size_t)cand[c] * DIM;
        float4 v0 = *reinterpret_cast<const float4*>(v + t * 8);
        float4 v1 = *reinterpret_cast<const float4*>(v + t * 8 + 4);
        float dp = x0.x*v0.x + x0.y*v0.y + x0.z*v0.z + x0.w*v0.w
                 + x1.x*v1.x + x1.y*v1.y + x1.z*v1.z + x1.w*v1.w;
        float vp = v0.x*v0.x + v0.y*v0.y + v0.z*v0.z + v0.w*v0.w
                 + v1.x*v1.x + v1.y*v1.y + v1.z*v1.z + v1.w*v1.w;
        const float dot = block_sum(dp, sbuf, t);
        const float vv  = block_sum(vp, sbuf, t);
        const float s = dot / (xn * fmaxf(sqrtf(vv), 1e-12f));
        u64 key = pack_key(s, (unsigned int)cand[c]);
        if (key > bestkey) { bestkey = key; bestid = cand[c]; bestsa = vv; }
    }

    const float* a = Vg + (size_t)bestid * DIM;
    float4 a0 = *reinterpret_cast<const float4*>(a + t * 8);
    float4 a1 = *reinterpret_cast<const float4*>(a + t * 8 + 4);
    float4 d0 = make_float4(x0.x-a0.x, x0.y-a0.y, x0.z-a0.z, x0.w-a0.w);
    float4 d1 = make_float4(x1.x-a1.x, x1.y-a1.y, x1.z-a1.z, x1.w-a1.w);
    float sop = d0.x*d0.x + d0.y*d0.y + d0.z*d0.z + d0.w*d0.w
              + d1.x*d1.x + d1.y*d1.y + d1.z*d1.z + d1.w*d1.w;
    const float so = block_sum(sop, sbuf, t);
    const float scale = fminf(0.1f * sqrtf(bestsa) / (sqrtf(so) + 1e-8f), 1.0f);

    float4 o0 = make_float4(a0.x + d0.x*scale, a0.y + d0.y*scale,
                            a0.z + d0.z*scale, a0.w + d0.w*scale);
    float4 o1 = make_float4(a1.x + d1.x*scale, a1.y + d1.y*scale,
                            a1.z + d1.z*scale, a1.w + d1.w*scale);
    float* o = outx + (size_t)row * DIM + t * 8;
    *reinterpret_cast<float4*>(o)     = o0;
    *reinterpret_cast<float4*>(o + 4) = o1;
    if (t == 0) outid[row] = (float)bestid;
}

extern "C" void kernel_launch(void* const* d_in, const int* in_sizes, int n_in,
                              void* d_out, int out_size, void* d_ws, size_t ws_size,
                              hipStream_t stream) {
    const float* X  = (const float*)d_in[0];
    const float* Vg = (const float*)d_in[1];
    const int M  = in_sizes[0] / DIM;   // 8192
    const int NV = in_sizes[1] / DIM;   // 32000

    char* ws = (char*)d_ws;
    u64* R = (u64*)ws;                                   // NLEV levels x M
    size_t off = (size_t)NLEV * M * sizeof(u64);         // 512 KB
    float* invnorm = (float*)(ws + off);
    off += ((size_t)NV * sizeof(float) + 255) & ~255ull; // 128 KB
    signed char* Xq = (signed char*)(ws + off);
    off += (size_t)M * DIM;                              // 16 MB
    signed char* Vq = (signed char*)(ws + off);
    off += (size_t)NV * DIM;                             // 64 MB
    const bool fast = (ws_size >= off);

    float* outx  = (float*)d_out;
    float* outid = outx + (size_t)M * DIM;

    hipMemsetAsync(R, 0, (size_t)NLEV * M * sizeof(u64), stream);
    vocab_invnorm_kernel<<<NV, 256, 0, stream>>>(Vg, invnorm);

    if (fast) {
        convert_x_q<<<(M / BM) * KSTEPS, 256, 0, stream>>>(X, Xq);            // 64*32
        convert_v_q<<<(NV / BN) * KSTEPS, 256, 0, stream>>>(Vg, invnorm, Vq); // 125*32
        dim3 grid((NV / BN) * (M / BM));    // 125*64 = 8000 blocks
        sim_i8_pipe<<<grid, 512, 0, stream>>>(Xq, Vq, R, M);
    } else {
        dim3 gridf((NV / 128) * (M / 128)); // 16000 blocks
        sim_coarse_fallback<<<gridf, 256, 0, stream>>>(X, Vg, invnorm,
                                                       R, R + M, R + 2 * M);
    }

    rescue_finalize_kernel<<<M, 256, 0, stream>>>(X, Vg, R, M, NV, outx, outid);
}

// Round 16
// 1584.446 us; speedup vs baseline: 1.0258x; 1.0258x over previous
//
#include <hip/hip_runtime.h>
#include <hip/hip_bf16.h>

#define DIM 2048
#define BM 256
#define BN 128
#define BK 64
#define KSTEPS (DIM / BK)          // 32 K-tiles
#define XT_BYTES (BM * BK)         // 16384 B  (A tile, [256][64])
#define VT_BYTES (BN * BK)         // 8192 B   (B tile, [128][64])
#define NLEV 8                     // global top-8 cascade

typedef _Float16 f16x8 __attribute__((ext_vector_type(8)));
typedef float f32x4 __attribute__((ext_vector_type(4)));
typedef int i32x4 __attribute__((ext_vector_type(4)));
typedef unsigned long long u64;

#define INV_SX 27.6f               // X scale: clip at 4.60 sigma
#define INV_SVN 1150.0f            // normalized-V scale: clip at |vn|=0.1104

typedef const unsigned int __attribute__((address_space(1))) gu32;
typedef unsigned int __attribute__((address_space(3))) lu32;

__device__ __forceinline__ void gl_lds16(const void* g, void* l) {
    __builtin_amdgcn_global_load_lds((gu32*)g, (lu32*)l, 16, 0, 0);
}

// Monotone float->uint map; pack (val, col) so u64 max = (max val, first col on ties)
__device__ __forceinline__ u64 pack_key(float v, unsigned int col) {
    unsigned int b = __float_as_uint(v);
    b ^= (unsigned int)(((int)b >> 31)) | 0x80000000u;
    return ((u64)b << 32) | (u64)(~col);
}
// integer-dot key: monotone in dot, lowest col on ties
__device__ __forceinline__ u64 pack_key_i(int dot, unsigned int col) {
    unsigned int b = (unsigned int)dot ^ 0x80000000u;
    return ((u64)b << 32) | (u64)(~col);
}
__device__ __forceinline__ u64 umax64(u64 a, u64 b) { return a > b ? a : b; }
__device__ __forceinline__ u64 umin64(u64 a, u64 b) { return a < b ? a : b; }

// lock-free exact top-N cascade (order-independent => deterministic).
__device__ __forceinline__ void cascadeN(u64* Rrow, int stride, u64 k) {
    if (k <= Rrow[(NLEV - 1) * stride]) return;   // monotone prune (safe)
#pragma unroll
    for (int l = 0; l < NLEV; ++l) {
        u64 old = atomicMax(&Rrow[l * stride], k);
        k = umin64(k, old);
        if (!k) return;
    }
}
__device__ __forceinline__ void cascade3(u64* r1, u64* r2, u64* r3, u64 k) {
    u64 old = atomicMax(r1, k);
    k = umin64(k, old);
    if (k) {
        old = atomicMax(r2, k);
        k = umin64(k, old);
        if (k) atomicMax(r3, k);
    }
}

// tile image: 128B lines (row pairs of 64B), 8x16B slots, slot ^= line&7
// (byte-identical to the r6-r15 verified image)
__device__ __forceinline__ int toff(int row, int kg) {
    const int line = row >> 1;
    const int s8 = ((row & 1) << 2) | kg;
    return line * 128 + ((s8 ^ (line & 7)) << 4);   // byte offset
}

// old f16 swizzle (used by the 128^2 fallback kernel only)
__device__ __forceinline__ int swz(int row, int slot) {
    return row * 32 + (slot ^ ((row >> 1) & 3)) * 8;
}

__global__ void vocab_invnorm_kernel(const float* __restrict__ Vg,
                                     float* __restrict__ invnorm) {
    const int v = blockIdx.x;
    const int t = threadIdx.x;
    const float* row = Vg + (size_t)v * DIM;
    float4 f0 = *reinterpret_cast<const float4*>(row + t * 8);
    float4 f1 = *reinterpret_cast<const float4*>(row + t * 8 + 4);
    float s = f0.x*f0.x + f0.y*f0.y + f0.z*f0.z + f0.w*f0.w
            + f1.x*f1.x + f1.y*f1.y + f1.z*f1.z + f1.w*f1.w;
#pragma unroll
    for (int off = 32; off > 0; off >>= 1) s += __shfl_down(s, off);
    __shared__ float ls[4];
    const int lane = t & 63, w = t >> 6;
    if (lane == 0) ls[w] = s;
    __syncthreads();
    if (t == 0) {
        float tot = ls[0] + ls[1] + ls[2] + ls[3];
        invnorm[v] = 1.0f / fmaxf(sqrtf(tot), 1e-12f);
    }
}

__device__ __forceinline__ void q16pack(const float* xv, float s, int* out4) {
#pragma unroll
    for (int g = 0; g < 4; ++g) {
        int p = 0;
#pragma unroll
        for (int e = 0; e < 4; ++e) {
            int q = __float2int_rn(xv[g * 4 + e] * s);
            q = q > 127 ? 127 : (q < -127 ? -127 : q);
            p |= (q & 255) << (e * 8);
        }
        out4[g] = p;
    }
}

// X -> tiled i8, [256][64] tiles in the line/slot-swizzled image (fixed scale)
__global__ void convert_x_q(const float* __restrict__ X, signed char* __restrict__ Xq) {
    const int tile = blockIdx.x;          // mblk*32 + ks
    const int mblk = tile >> 5, ks = tile & 31;
    const float* src = X + (size_t)(mblk * BM) * DIM + ks * BK;
    signed char* dst = Xq + (size_t)tile * XT_BYTES;
    const int t = threadIdx.x;
#pragma unroll
    for (int u = 0; u < 4; ++u) {
        const int c = t + u * 256;        // 0..1023 chunk id (16 B each)
        const int line = c >> 3;
        const int s8 = (c & 7) ^ (line & 7);
        const int row = (line << 1) | (s8 >> 2);
        const int cs = s8 & 3;            // 16-elem slot
        const float* s = src + (size_t)row * DIM + cs * 16;
        float xv[16];
        *(float4*)(&xv[0])  = *(const float4*)(s);
        *(float4*)(&xv[4])  = *(const float4*)(s + 4);
        *(float4*)(&xv[8])  = *(const float4*)(s + 8);
        *(float4*)(&xv[12]) = *(const float4*)(s + 12);
        int q4[4];
        q16pack(xv, INV_SX, q4);
        *(int4*)(dst + c * 16) = make_int4(q4[0], q4[1], q4[2], q4[3]);
    }
}

// V -> tiled i8, [128][64] tiles (same image), normalized then fixed-scale
__global__ void convert_v_q(const float* __restrict__ Vg,
                            const float* __restrict__ invnorm,
                            signed char* __restrict__ Vq) {
    const int tile = blockIdx.x;          // nblk*32 + ks
    const int nblk = tile >> 5, ks = tile & 31;
    const float* src = Vg + (size_t)(nblk * BN) * DIM + ks * BK;
    signed char* dst = Vq + (size_t)tile * VT_BYTES;
    const int t = threadIdx.x;
#pragma unroll
    for (int u = 0; u < 2; ++u) {
        const int c = t + u * 256;        // 0..511
        const int line = c >> 3;
        const int s8 = (c & 7) ^ (line & 7);
        const int row = (line << 1) | (s8 >> 2);
        const int cs = s8 & 3;
        const float sc = invnorm[nblk * BN + row] * INV_SVN;
        const float* s = src + (size_t)row * DIM + cs * 16;
        float xv[16];
        *(float4*)(&xv[0])  = *(const float4*)(s);
        *(float4*)(&xv[4])  = *(const float4*)(s + 4);
        *(float4*)(&xv[8])  = *(const float4*)(s + 8);
        *(float4*)(&xv[12]) = *(const float4*)(s + 12);
        int q4[4];
        q16pack(xv, sc, q4);
        *(int4*)(dst + c * 16) = make_int4(q4[0], q4[1], q4[2], q4[3]);
    }
}

// 256 threads = 4 waves (2m x 2n), wave tile 128x64, block tile 256x128.
// r13 skeleton with FAT wave tiles: 32-MFMA cluster (~1300 cy) per wave-iter
// so 2 waves/SIMD cover the measured ~4000-cy memory wait. A in LDS (dbuf,
// DMA-staged, no duplication), B direct-to-reg prefetched d=1, one barrier
// per iter covered by the sibling block (2 blocks/CU).
__global__ __launch_bounds__(256, 2) void sim_i8_fat(
        const signed char* __restrict__ Xq, const signed char* __restrict__ Vq,
        u64* __restrict__ R, int M) {
    __shared__ alignas(16) signed char ldsA[2][XT_BYTES];   // 32 KB

    const int tid = threadIdx.x;
    // XCD-chunked bijective swizzle: 8000 blocks = 8 x 1000; m-fastest in chunk
    const int flat = blockIdx.x;
    const int idx  = (flat & 7) * 1000 + (flat >> 3);
    const int mblk = idx & 31;           // M/256 = 32
    const int nblk = idx >> 5;           // NV/128 = 250

    const int lane = tid & 63;
    const int w  = tid >> 6;             // 0..3
    const int wm = w >> 1, wn = w & 1;   // 2x2 wave grid; wave tile 128x64
    const int lr = lane & 15;
    const int kg = lane >> 4;

    const signed char* Atiles = Xq + (size_t)mblk * KSTEPS * XT_BYTES;
    const signed char* Btiles = Vq + (size_t)nblk * KSTEPS * VT_BYTES;

    i32x4 acc[8][4] = {};

    int offA[8], offB[4];
#pragma unroll
    for (int i = 0; i < 8; ++i) offA[i] = toff(wm * 128 + i * 16 + lr, kg);
#pragma unroll
    for (int j = 0; j < 4; ++j) offB[j] = toff(wn * 64 + j * 16 + lr, kg);

    // A staging: 1024 chunks of 16B, 256 threads -> 4 chunks/thread
    const int cA0 = tid * 16, cA1 = (tid + 256) * 16;
    const int cA2 = (tid + 512) * 16, cA3 = (tid + 768) * 16;

    // prologue: stage A tile 0; load B tile-0 fragments to registers
    gl_lds16(Atiles + cA0, &ldsA[0][cA0]);
    gl_lds16(Atiles + cA1, &ldsA[0][cA1]);
    gl_lds16(Atiles + cA2, &ldsA[0][cA2]);
    gl_lds16(Atiles + cA3, &ldsA[0][cA3]);
    i32x4 b0 = *(const i32x4*)(Btiles + offB[0]);
    i32x4 b1 = *(const i32x4*)(Btiles + offB[1]);
    i32x4 b2 = *(const i32x4*)(Btiles + offB[2]);
    i32x4 b3 = *(const i32x4*)(Btiles + offB[3]);
    __syncthreads();

    int cur = 0;
    for (int ks = 0; ks < KSTEPS; ++ks) {
        // prefetch next K-tile: B frags to regs, A tile to other LDS buffer
        const int nk = (ks + 1 < KSTEPS) ? (ks + 1) : ks;   // clamp (harmless reload)
        const signed char* bn = Btiles + (size_t)nk * VT_BYTES;
        i32x4 nb0 = *(const i32x4*)(bn + offB[0]);
        i32x4 nb1 = *(const i32x4*)(bn + offB[1]);
        i32x4 nb2 = *(const i32x4*)(bn + offB[2]);
        i32x4 nb3 = *(const i32x4*)(bn + offB[3]);
        if (ks + 1 < KSTEPS) {
            const signed char* an = Atiles + (size_t)(ks + 1) * XT_BYTES;
            gl_lds16(an + cA0, &ldsA[cur ^ 1][cA0]);
            gl_lds16(an + cA1, &ldsA[cur ^ 1][cA1]);
            gl_lds16(an + cA2, &ldsA[cur ^ 1][cA2]);
            gl_lds16(an + cA3, &ldsA[cur ^ 1][cA3]);
        }
#pragma unroll
        for (int i = 0; i < 8; ++i) {
            i32x4 ahf = *(const i32x4*)(&ldsA[cur][offA[i]]);
            acc[i][0] = __builtin_amdgcn_mfma_i32_16x16x64_i8(ahf, b0, acc[i][0], 0, 0, 0);
            acc[i][1] = __builtin_amdgcn_mfma_i32_16x16x64_i8(ahf, b1, acc[i][1], 0, 0, 0);
            acc[i][2] = __builtin_amdgcn_mfma_i32_16x16x64_i8(ahf, b2, acc[i][2], 0, 0, 0);
            acc[i][3] = __builtin_amdgcn_mfma_i32_16x16x64_i8(ahf, b3, acc[i][3], 0, 0, 0);
        }
        __syncthreads();   // drains vmcnt (A DMA + B prefetch) + lgkm; protects dbuf WAR
        b0 = nb0; b1 = nb1; b2 = nb2; b3 = nb3;
        cur ^= 1;
    }

    // epilogue: per-row top-2 within wave cols -> global top-8 cascade
    const int m0 = mblk * BM, n0 = nblk * BN;
#pragma unroll
    for (int i = 0; i < 8; ++i) {
#pragma unroll
        for (int r = 0; r < 4; ++r) {
            u64 k[4];
#pragma unroll
            for (int j = 0; j < 4; ++j)
                k[j] = pack_key_i(acc[i][j][r],
                                  (unsigned int)(n0 + wn * 64 + j * 16 + lr));
            u64 m01 = umax64(k[0], k[1]), q01 = umin64(k[0], k[1]);
            u64 m23 = umax64(k[2], k[3]), q23 = umin64(k[2], k[3]);
            u64 a1k = umax64(m01, m23);
            u64 a2k = umax64(umin64(m01, m23), umax64(q01, q23));
#pragma unroll
            for (int mask = 1; mask < 16; mask <<= 1) {
                u64 o1 = __shfl_xor(a1k, mask);
                u64 o2 = __shfl_xor(a2k, mask);
                u64 t1 = umax64(a1k, o1);
                a2k = umax64(umin64(a1k, o1), umax64(a2k, o2));
                a1k = t1;
            }
            if (lr == 0) {
                const int row = m0 + wm * 128 + i * 16 + kg * 4 + r;
                cascadeN(&R[row], M, a1k);
                cascadeN(&R[row], M, a2k);
            }
        }
    }
}

// ---------------- fallback (verified round-3 path, 128^2 f16; used if ws too small) ----------------
__global__ __launch_bounds__(256) void sim_coarse_fallback(
        const float* __restrict__ X, const float* __restrict__ Vg,
        const float* __restrict__ invnorm,
        u64* __restrict__ R1, u64* __restrict__ R2, u64* __restrict__ R3) {
    __shared__ alignas(16) _Float16 Ah[128 * 32];
    __shared__ alignas(16) _Float16 Bh[128 * 32];
    const int tid = threadIdx.x;
    const int flat = blockIdx.x;
    const int idx  = (flat & 7) * 2000 + (flat >> 3);
    const int panel = idx / 3200;
    const int w_    = idx - panel * 3200;
    const int mblk  = w_ & 63;
    const int nblk  = panel * 50 + (w_ >> 6);
    const int m0 = mblk * 128, n0 = nblk * 128;
    const int lane = tid & 63;
    const int w  = tid >> 6;
    const int wm = w >> 1, wn = w & 1;
    const int lr = lane & 15;
    const int kg = lane >> 4;
    const int sr  = tid >> 2;
    const int skc = tid & 3;
    const float* Aptr0 = X  + (size_t)(m0 + sr)      * DIM + skc * 8;
    const float* Aptr1 = X  + (size_t)(m0 + 64 + sr) * DIM + skc * 8;
    const float* Bptr0 = Vg + (size_t)(n0 + sr)      * DIM + skc * 8;
    const float* Bptr1 = Vg + (size_t)(n0 + 64 + sr) * DIM + skc * 8;
    float4 ra[4], rb[4];
    ra[0] = *(const float4*)(Aptr0);     ra[1] = *(const float4*)(Aptr0 + 4);
    ra[2] = *(const float4*)(Aptr1);     ra[3] = *(const float4*)(Aptr1 + 4);
    rb[0] = *(const float4*)(Bptr0);     rb[1] = *(const float4*)(Bptr0 + 4);
    rb[2] = *(const float4*)(Bptr1);     rb[3] = *(const float4*)(Bptr1 + 4);
    f32x4 acc[4][4] = {};
    const int wA0 = swz(sr, skc), wA1 = swz(sr + 64, skc);
    for (int ks = 0; ks < 64; ++ks) {
        {
            f16x8 h; float xv[8];
            *(float4*)(&xv[0]) = ra[0]; *(float4*)(&xv[4]) = ra[1];
#pragma unroll
            for (int e = 0; e < 8; ++e) h[e] = (_Float16)xv[e];
            *(f16x8*)(&Ah[wA0]) = h;
            *(float4*)(&xv[0]) = ra[2]; *(float4*)(&xv[4]) = ra[3];
#pragma unroll
            for (int e = 0; e < 8; ++e) h[e] = (_Float16)xv[e];
            *(f16x8*)(&Ah[wA1]) = h;
            *(float4*)(&xv[0]) = rb[0]; *(float4*)(&xv[4]) = rb[1];
#pragma unroll
            for (int e = 0; e < 8; ++e) h[e] = (_Float16)xv[e];
            *(f16x8*)(&Bh[wA0]) = h;
            *(float4*)(&xv[0]) = rb[2]; *(float4*)(&xv[4]) = rb[3];
#pragma unroll
            for (int e = 0; e < 8; ++e) h[e] = (_Float16)xv[e];
            *(f16x8*)(&Bh[wA1]) = h;
        }
        __syncthreads();
        if (ks + 1 < 64) {
            const int ko = (ks + 1) * 32;
            ra[0] = *(const float4*)(Aptr0 + ko); ra[1] = *(const float4*)(Aptr0 + ko + 4);
            ra[2] = *(const float4*)(Aptr1 + ko); ra[3] = *(const float4*)(Aptr1 + ko + 4);
            rb[0] = *(const float4*)(Bptr0 + ko); rb[1] = *(const float4*)(Bptr0 + ko + 4);
            rb[2] = *(const float4*)(Bptr1 + ko); rb[3] = *(const float4*)(Bptr1 + ko + 4);
        }
        f16x8 bhf[4];
#pragma unroll
        for (int j = 0; j < 4; ++j)
            bhf[j] = *(const f16x8*)(&Bh[swz(wn * 64 + j * 16 + lr, kg)]);
#pragma unroll
        for (int i = 0; i < 4; ++i) {
            f16x8 ahf = *(const f16x8*)(&Ah[swz(wm * 64 + i * 16 + lr, kg)]);
#pragma unroll
            for (int j = 0; j < 4; ++j)
                acc[i][j] = __builtin_amdgcn_mfma_f32_16x16x32_f16(ahf, bhf[j], acc[i][j], 0, 0, 0);
        }
        __syncthreads();
    }
    float inv[4];
#pragma unroll
    for (int j = 0; j < 4; ++j) inv[j] = invnorm[n0 + wn * 64 + j * 16 + lr];
#pragma unroll
    for (int i = 0; i < 4; ++i) {
#pragma unroll
        for (int r = 0; r < 4; ++r) {
            u64 k[4];
#pragma unroll
            for (int j = 0; j < 4; ++j)
                k[j] = pack_key(acc[i][j][r] * inv[j],
                                (unsigned int)(n0 + wn * 64 + j * 16 + lr));
            u64 m01 = umax64(k[0], k[1]), n01 = umin64(k[0], k[1]);
            u64 m23 = umax64(k[2], k[3]), n23 = umin64(k[2], k[3]);
            u64 a1 = umax64(m01, m23);
            u64 a2 = umax64(umin64(m01, m23), umax64(n01, n23));
#pragma unroll
            for (int mask = 1; mask < 16; mask <<= 1) {
                u64 b1 = __shfl_xor(a1, mask);
                u64 b2 = __shfl_xor(a2, mask);
                u64 t1 = umax64(a1, b1);
                a2 = umax64(umin64(a1, b1), umax64(a2, b2));
                a1 = t1;
            }
            if (lr == 0) {
                const int row = m0 + wm * 64 + i * 16 + kg * 4 + r;
                cascade3(&R1[row], &R2[row], &R3[row], a1);
                cascade3(&R1[row], &R2[row], &R3[row], a2);
            }
        }
    }
}

// block-wide sum reduction; returns total to ALL threads
__device__ __forceinline__ float block_sum(float v, float* sbuf, int t) {
#pragma unroll
    for (int off = 32; off > 0; off >>= 1) v += __shfl_down(v, off);
    const int lane = t & 63, w = t >> 6;
    __syncthreads();
    if (lane == 0) sbuf[w] = v;
    __syncthreads();
    return sbuf[0] + sbuf[1] + sbuf[2] + sbuf[3];
}

__global__ void rescue_finalize_kernel(const float* __restrict__ X,
                                       const float* __restrict__ Vg,
                                       const u64* __restrict__ R, int M, int NV,
                                       float* __restrict__ outx,
                                       float* __restrict__ outid) {
    const int row = blockIdx.x;
    const int t = threadIdx.x;
    __shared__ float sbuf[4];

    int cand[NLEV];
#pragma unroll
    for (int c = 0; c < NLEV; ++c) {
        unsigned int id = ~(unsigned int)(R[c * M + row] & 0xFFFFFFFFull);
        cand[c] = (id < (unsigned int)NV) ? (int)id : 0;
    }

    const float* x = X + (size_t)row * DIM;
    float4 x0 = *reinterpret_cast<const float4*>(x + t * 8);
    float4 x1 = *reinterpret_cast<const float4*>(x + t * 8 + 4);
    float xxp = x0.x*x0.x + x0.y*x0.y + x0.z*x0.z + x0.w*x0.w
              + x1.x*x1.x + x1.y*x1.y + x1.z*x1.z + x1.w*x1.w;
    const float xx = block_sum(xxp, sbuf, t);
    const float xn = fmaxf(sqrtf(xx), 1e-12f);

    u64 bestkey = 0ull;
    int bestid = cand[0];
    float bestsa = 0.f;
#pragma unroll
    for (int c = 0; c < NLEV; ++c) {
        const float* v = Vg + (size_t)cand[c] * DIM;
        float4 v0 = *reinterpret_cast<const float4*>(v + t * 8);
        float4 v1 = *reinterpret_cast<const float4*>(v + t * 8 + 4);
        float dp = x0.x*v0.x + x0.y*v0.y + x0.z*v0.z + x0.w*v0.w
                 + x1.x*v1.x + x1.y*v1.y + x1.z*v1.z + x1.w*v1.w;
        float vp = v0.x*v0.x + v0.y*v0.y + v0.z*v0.z + v0.w*v0.w
                 + v1.x*v1.x + v1.y*v1.y + v1.z*v1.z + v1.w*v1.w;
        const float dot = block_sum(dp, sbuf, t);
        const float vv  = block_sum(vp, sbuf, t);
        const float s = dot / (xn * fmaxf(sqrtf(vv), 1e-12f));
        u64 key = pack_key(s, (unsigned int)cand[c]);
        if (key > bestkey) { bestkey = key; bestid = cand[c]; bestsa = vv; }
    }

    const float* a = Vg + (size_t)bestid * DIM;
    float4 a0 = *reinterpret_cast<const float4*>(a + t * 8);
    float4 a1 = *reinterpret_cast<const float4*>(a + t * 8 + 4);
    float4 d0 = make_float4(x0.x-a0.x, x0.y-a0.y, x0.z-a0.z, x0.w-a0.w);
    float4 d1 = make_float4(x1.x-a1.x, x1.y-a1.y, x1.z-a1.z, x1.w-a1.w);
    float sop = d0.x*d0.x + d0.y*d0.y + d0.z*d0.z + d0.w*d0.w
              + d1.x*d1.x + d1.y*d1.y + d1.z*d1.z + d1.w*d1.w;
    const float so = block_sum(sop, sbuf, t);
    const float scale = fminf(0.1f * sqrtf(bestsa) / (sqrtf(so) + 1e-8f), 1.0f);

    float4 o0 = make_float4(a0.x + d0.x*scale, a0.y + d0.y*scale,
                            a0.z + d0.z*scale, a0.w + d0.w*scale);
    float4 o1 = make_float4(a1.x + d1.x*scale, a1.y + d1.y*scale,
                            a1.z + d1.z*scale, a1.w + d1.w*scale);
    float* o = outx + (size_t)row * DIM + t * 8;
    *reinterpret_cast<float4*>(o)     = o0;
    *reinterpret_cast<float4*>(o + 4) = o1;
    if (t == 0) outid[row] = (float)bestid;
}

extern "C" void kernel_launch(void* const* d_in, const int* in_sizes, int n_in,
                              void* d_out, int out_size, void* d_ws, size_t ws_size,
                              hipStream_t stream) {
    const float* X  = (const float*)d_in[0];
    const float* Vg = (const float*)d_in[1];
    const int M  = in_sizes[0] / DIM;   // 8192
    const int NV = in_sizes[1] / DIM;   // 32000

    char* ws = (char*)d_ws;
    u64* R = (u64*)ws;                                   // NLEV levels x M
    size_t off = (size_t)NLEV * M * sizeof(u64);         // 512 KB
    float* invnorm = (float*)(ws + off);
    off += ((size_t)NV * sizeof(float) + 255) & ~255ull; // 128 KB
    signed char* Xq = (signed char*)(ws + off);
    off += (size_t)M * DIM;                              // 16 MB
    signed char* Vq = (signed char*)(ws + off);
    off += (size_t)NV * DIM;                             // 64 MB
    const bool fast = (ws_size >= off);

    float* outx  = (float*)d_out;
    float* outid = outx + (size_t)M * DIM;

    hipMemsetAsync(R, 0, (size_t)NLEV * M * sizeof(u64), stream);
    vocab_invnorm_kernel<<<NV, 256, 0, stream>>>(Vg, invnorm);

    if (fast) {
        convert_x_q<<<(M / BM) * KSTEPS, 256, 0, stream>>>(X, Xq);            // 32*32 = 1024
        convert_v_q<<<(NV / BN) * KSTEPS, 256, 0, stream>>>(Vg, invnorm, Vq); // 250*32 = 8000
        dim3 grid((NV / BN) * (M / BM));    // 250*32 = 8000 blocks
        sim_i8_fat<<<grid, 256, 0, stream>>>(Xq, Vq, R, M);
    } else {
        dim3 gridf((NV / 128) * (M / 128)); // 16000 blocks
        sim_coarse_fallback<<<gridf, 256, 0, stream>>>(X, Vg, invnorm,
                                                       R, R + M, R + 2 * M);
    }

    rescue_finalize_kernel<<<M, 256, 0, stream>>>(X, Vg, R, M, NV, outx, outid);
}

// Round 18
// 1238.092 us; speedup vs baseline: 1.3127x; 1.2797x over previous
//
#include <hip/hip_runtime.h>
#include <hip/hip_bf16.h>

#define DIM 2048
#define BM 128
#define BN 256
#define BK 64
#define KSTEPS (DIM / BK)          // 32 K-tiles
#define A_TILE_BYTES (BM * BK)     // 8192 B
#define B_TILE_BYTES (BN * BK)     // 16384 B
#define NLEV 8                     // global top-8 cascade

typedef _Float16 f16x8 __attribute__((ext_vector_type(8)));
typedef float f32x4 __attribute__((ext_vector_type(4)));
typedef int i32x4 __attribute__((ext_vector_type(4)));
typedef unsigned long long u64;

#define INV_SX 27.6f               // X scale: clip at 4.60 sigma
#define INV_SVN 1150.0f            // normalized-V scale: clip at |vn|=0.1104

typedef const unsigned int __attribute__((address_space(1))) gu32;
typedef unsigned int __attribute__((address_space(3))) lu32;

__device__ __forceinline__ void gl_lds16(const void* g, void* l) {
    __builtin_amdgcn_global_load_lds((gu32*)g, (lu32*)l, 16, 0, 0);
}

// Monotone float->uint map; pack (val, col) so u64 max = (max val, first col on ties)
__device__ __forceinline__ u64 pack_key(float v, unsigned int col) {
    unsigned int b = __float_as_uint(v);
    b ^= (unsigned int)(((int)b >> 31)) | 0x80000000u;
    return ((u64)b << 32) | (u64)(~col);
}
// integer-dot key: monotone in dot, lowest col on ties
__device__ __forceinline__ u64 pack_key_i(int dot, unsigned int col) {
    unsigned int b = (unsigned int)dot ^ 0x80000000u;
    return ((u64)b << 32) | (u64)(~col);
}
__device__ __forceinline__ u64 umax64(u64 a, u64 b) { return a > b ? a : b; }
__device__ __forceinline__ u64 umin64(u64 a, u64 b) { return a < b ? a : b; }

// lock-free exact top-N cascade (order-independent => deterministic).
__device__ __forceinline__ void cascadeN(u64* Rrow, int stride, u64 k) {
    if (k <= Rrow[(NLEV - 1) * stride]) return;   // monotone prune (safe)
#pragma unroll
    for (int l = 0; l < NLEV; ++l) {
        u64 old = atomicMax(&Rrow[l * stride], k);
        k = umin64(k, old);
        if (!k) return;
    }
}
__device__ __forceinline__ void cascade3(u64* r1, u64* r2, u64* r3, u64 k) {
    u64 old = atomicMax(r1, k);
    k = umin64(k, old);
    if (k) {
        old = atomicMax(r2, k);
        k = umin64(k, old);
        if (k) atomicMax(r3, k);
    }
}

// tile image: 128B lines (row pairs of 64B), 8x16B slots, slot ^= line&7
// (byte-identical to the r6-r16 verified image)
__device__ __forceinline__ int toff(int row, int kg) {
    const int line = row >> 1;
    const int s8 = ((row & 1) << 2) | kg;
    return line * 128 + ((s8 ^ (line & 7)) << 4);   // byte offset
}

// old f16 swizzle (used by the 128^2 fallback kernel only)
__device__ __forceinline__ int swz(int row, int slot) {
    return row * 32 + (slot ^ ((row >> 1) & 3)) * 8;
}

__global__ void vocab_invnorm_kernel(const float* __restrict__ Vg,
                                     float* __restrict__ invnorm) {
    const int v = blockIdx.x;
    const int t = threadIdx.x;
    const float* row = Vg + (size_t)v * DIM;
    float4 f0 = *reinterpret_cast<const float4*>(row + t * 8);
    float4 f1 = *reinterpret_cast<const float4*>(row + t * 8 + 4);
    float s = f0.x*f0.x + f0.y*f0.y + f0.z*f0.z + f0.w*f0.w
            + f1.x*f1.x + f1.y*f1.y + f1.z*f1.z + f1.w*f1.w;
#pragma unroll
    for (int off = 32; off > 0; off >>= 1) s += __shfl_down(s, off);
    __shared__ float ls[4];
    const int lane = t & 63, w = t >> 6;
    if (lane == 0) ls[w] = s;
    __syncthreads();
    if (t == 0) {
        float tot = ls[0] + ls[1] + ls[2] + ls[3];
        invnorm[v] = 1.0f / fmaxf(sqrtf(tot), 1e-12f);
    }
}

__device__ __forceinline__ void q16pack(const float* xv, float s, int* out4) {
#pragma unroll
    for (int g = 0; g < 4; ++g) {
        int p = 0;
#pragma unroll
        for (int e = 0; e < 4; ++e) {
            int q = __float2int_rn(xv[g * 4 + e] * s);
            q = q > 127 ? 127 : (q < -127 ? -127 : q);
            p |= (q & 255) << (e * 8);
        }
        out4[g] = p;
    }
}

// X -> tiled i8, [128][64] tiles in the line/slot-swizzled image (fixed scale)
__global__ void convert_x_q(const float* __restrict__ X, signed char* __restrict__ Xq) {
    const int tile = blockIdx.x;          // mblk*32 + ks
    const int mblk = tile >> 5, ks = tile & 31;
    const float* src = X + (size_t)(mblk * BM) * DIM + ks * BK;
    signed char* dst = Xq + (size_t)tile * A_TILE_BYTES;
    const int t = threadIdx.x;
#pragma unroll
    for (int u = 0; u < 2; ++u) {
        const int c = t + u * 256;        // 0..511 chunk id (16 B each)
        const int line = c >> 3;
        const int s8 = (c & 7) ^ (line & 7);
        const int row = (line << 1) | (s8 >> 2);
        const int cs = s8 & 3;            // 16-elem slot
        const float* s = src + (size_t)row * DIM + cs * 16;
        float xv[16];
        *(float4*)(&xv[0])  = *(const float4*)(s);
        *(float4*)(&xv[4])  = *(const float4*)(s + 4);
        *(float4*)(&xv[8])  = *(const float4*)(s + 8);
        *(float4*)(&xv[12]) = *(const float4*)(s + 12);
        int q4[4];
        q16pack(xv, INV_SX, q4);
        *(int4*)(dst + c * 16) = make_int4(q4[0], q4[1], q4[2], q4[3]);
    }
}

// V -> tiled i8, [256][64] tiles (same image), normalized then fixed-scale
__global__ void convert_v_q(const float* __restrict__ Vg,
                            const float* __restrict__ invnorm,
                            signed char* __restrict__ Vq) {
    const int tile = blockIdx.x;          // nblk*32 + ks
    const int nblk = tile >> 5, ks = tile & 31;
    const float* src = Vg + (size_t)(nblk * BN) * DIM + ks * BK;
    signed char* dst = Vq + (size_t)tile * B_TILE_BYTES;
    const int t = threadIdx.x;
#pragma unroll
    for (int u = 0; u < 4; ++u) {
        const int c = t + u * 256;        // 0..1023
        const int line = c >> 3;
        const int s8 = (c & 7) ^ (line & 7);
        const int row = (line << 1) | (s8 >> 2);
        const int cs = s8 & 3;
        const float sc = invnorm[nblk * BN + row] * INV_SVN;
        const float* s = src + (size_t)row * DIM + cs * 16;
        float xv[16];
        *(float4*)(&xv[0])  = *(const float4*)(s);
        *(float4*)(&xv[4])  = *(const float4*)(s + 4);
        *(float4*)(&xv[8])  = *(const float4*)(s + 8);
        *(float4*)(&xv[12]) = *(const float4*)(s + 12);
        int q4[4];
        q16pack(xv, sc, q4);
        *(int4*)(dst + c * 16) = make_int4(q4[0], q4[1], q4[2], q4[3]);
    }
}

// 512 threads = 8 waves (2m x 4n), wave tile 64x64, block tile 128x256.
// r13 skeleton + 4-slot A-ring with COUNTED vmcnt(9) (order-robust: covers
// DMA(ks) for ANY intra-iteration vmem permutation) and raw s_barrier
// followed by sched_barrier(0) (rule-18 fence: pins ds_reads below the
// barrier). DMA stays ~2 iterations in flight; never drained to 0 mid-loop.
__global__ __launch_bounds__(512, 4) void sim_i8_ring(
        const signed char* __restrict__ Xq, const signed char* __restrict__ Vq,
        u64* __restrict__ R, int M) {
    __shared__ alignas(16) signed char ldsA[4][A_TILE_BYTES];   // 32 KB

    const int tid = threadIdx.x;
    // XCD-chunked bijective swizzle: 8000 blocks = 8 x 1000; m-fastest in chunk
    const int flat = blockIdx.x;
    const int idx  = (flat & 7) * 1000 + (flat >> 3);
    const int mblk = idx & 63;           // M/128 = 64
    const int nblk = idx >> 6;           // NV/256 = 125

    const int lane = tid & 63;
    const int w  = tid >> 6;             // 0..7
    const int wm = w >> 2, wn = w & 3;   // 2x4 wave grid; wave tile 64x64
    const int lr = lane & 15;
    const int kg = lane >> 4;

    const signed char* Atiles = Xq + (size_t)mblk * KSTEPS * A_TILE_BYTES;
    const signed char* Btiles = Vq + (size_t)nblk * KSTEPS * B_TILE_BYTES;

    i32x4 acc[4][4] = {};

    int offA[4], offB[4];
#pragma unroll
    for (int i = 0; i < 4; ++i) offA[i] = toff(wm * 64 + i * 16 + lr, kg);
#pragma unroll
    for (int j = 0; j < 4; ++j) offB[j] = toff(wn * 64 + j * 16 + lr, kg);

    const int cA = tid * 16;             // A staging: 512 chunks of 16B, 1/thread

    // prologue: DMA A(0)->slot0, A(1)->slot1; B(0) frags -> regs; drain once
    gl_lds16(Atiles + cA,                &ldsA[0][cA]);
    gl_lds16(Atiles + A_TILE_BYTES + cA, &ldsA[1][cA]);
    i32x4 b0 = *(const i32x4*)(Btiles + offB[0]);
    i32x4 b1 = *(const i32x4*)(Btiles + offB[1]);
    i32x4 b2 = *(const i32x4*)(Btiles + offB[2]);
    i32x4 b3 = *(const i32x4*)(Btiles + offB[3]);
    asm volatile("s_waitcnt vmcnt(0)" ::: "memory");
    __builtin_amdgcn_s_barrier();
    __builtin_amdgcn_sched_barrier(0);

    for (int ks = 0; ks < KSTEPS; ++ks) {
        // issue B(ks+1) frags -> regs (clamped tail: harmless reload)
        const int nk = (ks + 1 < KSTEPS) ? (ks + 1) : (KSTEPS - 1);
        const signed char* bn = Btiles + (size_t)nk * B_TILE_BYTES;
        i32x4 nb0 = *(const i32x4*)(bn + offB[0]);
        i32x4 nb1 = *(const i32x4*)(bn + offB[1]);
        i32x4 nb2 = *(const i32x4*)(bn + offB[2]);
        i32x4 nb3 = *(const i32x4*)(bn + offB[3]);
        // issue DMA A(ks+2) -> slot (ks+2)&3 (clamped src; dead slot at tail, WAR-safe)
        const int ak = (ks + 2 < KSTEPS) ? (ks + 2) : (KSTEPS - 1);
        gl_lds16(Atiles + (size_t)ak * A_TILE_BYTES + cA, &ldsA[(ks + 2) & 3][cA]);
        // counted wait: 5 vmem ops/iter; vmcnt(9) retires 5ks-4 ops, which
        // covers iter ks-2's whole block (last index 5ks-6) for ANY intra-iter
        // order => DMA A(ks) landed. Barrier: slot ks&3 complete for ALL waves.
        asm volatile("s_waitcnt vmcnt(9)" ::: "memory");
        __builtin_amdgcn_s_barrier();
        __builtin_amdgcn_sched_barrier(0);   // rule-18 fence: no ds_read hoist

        const signed char* As = &ldsA[ks & 3][0];
#pragma unroll
        for (int i = 0; i < 4; ++i) {
            i32x4 ahf = *(const i32x4*)(As + offA[i]);
            acc[i][0] = __builtin_amdgcn_mfma_i32_16x16x64_i8(ahf, b0, acc[i][0], 0, 0, 0);
            acc[i][1] = __builtin_amdgcn_mfma_i32_16x16x64_i8(ahf, b1, acc[i][1], 0, 0, 0);
            acc[i][2] = __builtin_amdgcn_mfma_i32_16x16x64_i8(ahf, b2, acc[i][2], 0, 0, 0);
            acc[i][3] = __builtin_amdgcn_mfma_i32_16x16x64_i8(ahf, b3, acc[i][3], 0, 0, 0);
        }
        b0 = nb0; b1 = nb1; b2 = nb2; b3 = nb3;
    }

    // epilogue: per-row top-2 within wave cols -> global top-8 cascade
    const int m0 = mblk * BM, n0 = nblk * BN;
#pragma unroll
    for (int i = 0; i < 4; ++i) {
#pragma unroll
        for (int r = 0; r < 4; ++r) {
            u64 k[4];
#pragma unroll
            for (int j = 0; j < 4; ++j)
                k[j] = pack_key_i(acc[i][j][r],
                                  (unsigned int)(n0 + wn * 64 + j * 16 + lr));
            u64 m01 = umax64(k[0], k[1]), q01 = umin64(k[0], k[1]);
            u64 m23 = umax64(k[2], k[3]), q23 = umin64(k[2], k[3]);
            u64 a1k = umax64(m01, m23);
            u64 a2k = umax64(umin64(m01, m23), umax64(q01, q23));
#pragma unroll
            for (int mask = 1; mask < 16; mask <<= 1) {
                u64 o1 = __shfl_xor(a1k, mask);
                u64 o2 = __shfl_xor(a2k, mask);
                u64 t1 = umax64(a1k, o1);
                a2k = umax64(umin64(a1k, o1), umax64(a2k, o2));
                a1k = t1;
            }
            if (lr == 0) {
                const int row = m0 + wm * 64 + i * 16 + kg * 4 + r;
                cascadeN(&R[row], M, a1k);
                cascadeN(&R[row], M, a2k);
            }
        }
    }
}

// ---------------- fallback (verified round-3 path, 128^2 f16; used if ws too small) ----------------
__global__ __launch_bounds__(256) void sim_coarse_fallback(
        const float* __restrict__ X, const float* __restrict__ Vg,
        const float* __restrict__ invnorm,
        u64* __restrict__ R1, u64* __restrict__ R2, u64* __restrict__ R3) {
    __shared__ alignas(16) _Float16 Ah[128 * 32];
    __shared__ alignas(16) _Float16 Bh[128 * 32];
    const int tid = threadIdx.x;
    const int flat = blockIdx.x;
    const int idx  = (flat & 7) * 2000 + (flat >> 3);
    const int panel = idx / 3200;
    const int w_    = idx - panel * 3200;
    const int mblk  = w_ & 63;
    const int nblk  = panel * 50 + (w_ >> 6);
    const int m0 = mblk * 128, n0 = nblk * 128;
    const int lane = tid & 63;
    const int w  = tid >> 6;
    const int wm = w >> 1, wn = w & 1;
    const int lr = lane & 15;
    const int kg = lane >> 4;
    const int sr  = tid >> 2;
    const int skc = tid & 3;
    const float* Aptr0 = X  + (size_t)(m0 + sr)      * DIM + skc * 8;
    const float* Aptr1 = X  + (size_t)(m0 + 64 + sr) * DIM + skc * 8;
    const float* Bptr0 = Vg + (size_t)(n0 + sr)      * DIM + skc * 8;
    const float* Bptr1 = Vg + (size_t)(n0 + 64 + sr) * DIM + skc * 8;
    float4 ra[4], rb[4];
    ra[0] = *(const float4*)(Aptr0);     ra[1] = *(const float4*)(Aptr0 + 4);
    ra[2] = *(const float4*)(Aptr1);     ra[3] = *(const float4*)(Aptr1 + 4);
    rb[0] = *(const float4*)(Bptr0);     rb[1] = *(const float4*)(Bptr0 + 4);
    rb[2] = *(const float4*)(Bptr1);     rb[3] = *(const float4*)(Bptr1 + 4);
    f32x4 acc[4][4] = {};
    const int wA0 = swz(sr, skc), wA1 = swz(sr + 64, skc);
    for (int ks = 0; ks < 64; ++ks) {
        {
            f16x8 h; float xv[8];
            *(float4*)(&xv[0]) = ra[0]; *(float4*)(&xv[4]) = ra[1];
#pragma unroll
            for (int e = 0; e < 8; ++e) h[e] = (_Float16)xv[e];
            *(f16x8*)(&Ah[wA0]) = h;
            *(float4*)(&xv[0]) = ra[2]; *(float4*)(&xv[4]) = ra[3];
#pragma unroll
            for (int e = 0; e < 8; ++e) h[e] = (_Float16)xv[e];
            *(f16x8*)(&Ah[wA1]) = h;
            *(float4*)(&xv[0]) = rb[0]; *(float4*)(&xv[4]) = rb[1];
#pragma unroll
            for (int e = 0; e < 8; ++e) h[e] = (_Float16)xv[e];
            *(f16x8*)(&Bh[wA0]) = h;
            *(float4*)(&xv[0]) = rb[2]; *(float4*)(&xv[4]) = rb[3];
#pragma unroll
            for (int e = 0; e < 8; ++e) h[e] = (_Float16)xv[e];
            *(f16x8*)(&Bh[wA1]) = h;
        }
        __syncthreads();
        if (ks + 1 < 64) {
            const int ko = (ks + 1) * 32;
            ra[0] = *(const float4*)(Aptr0 + ko); ra[1] = *(const float4*)(Aptr0 + ko + 4);
            ra[2] = *(const float4*)(Aptr1 + ko); ra[3] = *(const float4*)(Aptr1 + ko + 4);
            rb[0] = *(const float4*)(Bptr0 + ko); rb[1] = *(const float4*)(Bptr0 + ko + 4);
            rb[2] = *(const float4*)(Bptr1 + ko); rb[3] = *(const float4*)(Bptr1 + ko + 4);
        }
        f16x8 bhf[4];
#pragma unroll
        for (int j = 0; j < 4; ++j)
            bhf[j] = *(const f16x8*)(&Bh[swz(wn * 64 + j * 16 + lr, kg)]);
#pragma unroll
        for (int i = 0; i < 4; ++i) {
            f16x8 ahf = *(const f16x8*)(&Ah[swz(wm * 64 + i * 16 + lr, kg)]);
#pragma unroll
            for (int j = 0; j < 4; ++j)
                acc[i][j] = __builtin_amdgcn_mfma_f32_16x16x32_f16(ahf, bhf[j], acc[i][j], 0, 0, 0);
        }
        __syncthreads();
    }
    float inv[4];
#pragma unroll
    for (int j = 0; j < 4; ++j) inv[j] = invnorm[n0 + wn * 64 + j * 16 + lr];
#pragma unroll
    for (int i = 0; i < 4; ++i) {
#pragma unroll
        for (int r = 0; r < 4; ++r) {
            u64 k[4];
#pragma unroll
            for (int j = 0; j < 4; ++j)
                k[j] = pack_key(acc[i][j][r] * inv[j],
                                (unsigned int)(n0 + wn * 64 + j * 16 + lr));
            u64 m01 = umax64(k[0], k[1]), n01 = umin64(k[0], k[1]);
            u64 m23 = umax64(k[2], k[3]), n23 = umin64(k[2], k[3]);
            u64 a1 = umax64(m01, m23);
            u64 a2 = umax64(umin64(m01, m23), umax64(n01, n23));
#pragma unroll
            for (int mask = 1; mask < 16; mask <<= 1) {
                u64 b1 = __shfl_xor(a1, mask);
                u64 b2 = __shfl_xor(a2, mask);
                u64 t1 = umax64(a1, b1);
                a2 = umax64(umin64(a1, b1), umax64(a2, b2));
                a1 = t1;
            }
            if (lr == 0) {
                const int row = m0 + wm * 64 + i * 16 + kg * 4 + r;
                cascade3(&R1[row], &R2[row], &R3[row], a1);
                cascade3(&R1[row], &R2[row], &R3[row], a2);
            }
        }
    }
}

// block-wide sum reduction; returns total to ALL threads
__device__ __forceinline__ float block_sum(float v, float* sbuf, int t) {
#pragma unroll
    for (int off = 32; off > 0; off >>= 1) v += __shfl_down(v, off);
    const int lane = t & 63, w = t >> 6;
    __syncthreads();
    if (lane == 0) sbuf[w] = v;
    __syncthreads();
    return sbuf[0] + sbuf[1] + sbuf[2] + sbuf[3];
}

__global__ void rescue_finalize_kernel(const float* __restrict__ X,
                                       const float* __restrict__ Vg,
                                       const u64* __restrict__ R, int M, int NV,
                                       float* __restrict__ outx,
                                       float* __restrict__ outid) {
    const int row = blockIdx.x;
    const int t = threadIdx.x;
    __shared__ float sbuf[4];

    int cand[NLEV];
#pragma unroll
    for (int c = 0; c < NLEV; ++c) {
        unsigned int id = ~(unsigned int)(R[c * M + row] & 0xFFFFFFFFull);
        cand[c] = (id < (unsigned int)NV) ? (int)id : 0;
    }

    const float* x = X + (size_t)row * DIM;
    float4 x0 = *reinterpret_cast<const float4*>(x + t * 8);
    float4 x1 = *reinterpret_cast<const float4*>(x + t * 8 + 4);
    float xxp = x0.x*x0.x + x0.y*x0.y + x0.z*x0.z + x0.w*x0.w
              + x1.x*x1.x + x1.y*x1.y + x1.z*x1.z + x1.w*x1.w;
    const float xx = block_sum(xxp, sbuf, t);
    const float xn = fmaxf(sqrtf(xx), 1e-12f);

    u64 bestkey = 0ull;
    int bestid = cand[0];
    float bestsa = 0.f;
#pragma unroll
    for (int c = 0; c < NLEV; ++c) {
        const float* v = Vg + (size_t)cand[c] * DIM;
        float4 v0 = *reinterpret_cast<const float4*>(v + t * 8);
        float4 v1 = *reinterpret_cast<const float4*>(v + t * 8 + 4);
        float dp = x0.x*v0.x + x0.y*v0.y + x0.z*v0.z + x0.w*v0.w
                 + x1.x*v1.x + x1.y*v1.y + x1.z*v1.z + x1.w*v1.w;
        float vp = v0.x*v0.x + v0.y*v0.y + v0.z*v0.z + v0.w*v0.w
                 + v1.x*v1.x + v1.y*v1.y + v1.z*v1.z + v1.w*v1.w;
        const float dot = block_sum(dp, sbuf, t);
        const float vv  = block_sum(vp, sbuf, t);
        const float s = dot / (xn * fmaxf(sqrtf(vv), 1e-12f));
        u64 key = pack_key(s, (unsigned int)cand[c]);
        if (key > bestkey) { bestkey = key; bestid = cand[c]; bestsa = vv; }
    }

    const float* a = Vg + (size_t)bestid * DIM;
    float4 a0 = *reinterpret_cast<const float4*>(a + t * 8);
    float4 a1 = *reinterpret_cast<const float4*>(a + t * 8 + 4);
    float4 d0 = make_float4(x0.x-a0.x, x0.y-a0.y, x0.z-a0.z, x0.w-a0.w);
    float4 d1 = make_float4(x1.x-a1.x, x1.y-a1.y, x1.z-a1.z, x1.w-a1.w);
    float sop = d0.x*d0.x + d0.y*d0.y + d0.z*d0.z + d0.w*d0.w
              + d1.x*d1.x + d1.y*d1.y + d1.z*d1.z + d1.w*d1.w;
    const float so = block_sum(sop, sbuf, t);
    const float scale = fminf(0.1f * sqrtf(bestsa) / (sqrtf(so) + 1e-8f), 1.0f);

    float4 o0 = make_float4(a0.x + d0.x*scale, a0.y + d0.y*scale,
                            a0.z + d0.z*scale, a0.w + d0.w*scale);
    float4 o1 = make_float4(a1.x + d1.x*scale, a1.y + d1.y*scale,
                            a1.z + d1.z*scale, a1.w + d1.w*scale);
    float* o = outx + (size_t)row * DIM + t * 8;
    *reinterpret_cast<float4*>(o)     = o0;
    *reinterpret_cast<float4*>(o + 4) = o1;
    if (t == 0) outid[row] = (float)bestid;
}

extern "C" void kernel_launch(void* const* d_in, const int* in_sizes, int n_in,
                              void* d_out, int out_size, void* d_ws, size_t ws_size,
                              hipStream_t stream) {
    const float* X  = (const float*)d_in[0];
    const float* Vg = (const float*)d_in[1];
    const int M  = in_sizes[0] / DIM;   // 8192
    const int NV = in_sizes[1] / DIM;   // 32000

    char* ws = (char*)d_ws;
    u64* R = (u64*)ws;                                   // NLEV levels x M
    size_t off = (size_t)NLEV * M * sizeof(u64);         // 512 KB
    float* invnorm = (float*)(ws + off);
    off += ((size_t)NV * sizeof(float) + 255) & ~255ull; // 128 KB
    signed char* Xq = (signed char*)(ws + off);
    off += (size_t)M * DIM;                              // 16 MB
    signed char* Vq = (signed char*)(ws + off);
    off += (size_t)NV * DIM;                             // 64 MB
    const bool fast = (ws_size >= off);

    float* outx  = (float*)d_out;
    float* outid = outx + (size_t)M * DIM;

    hipMemsetAsync(R, 0, (size_t)NLEV * M * sizeof(u64), stream);
    vocab_invnorm_kernel<<<NV, 256, 0, stream>>>(Vg, invnorm);

    if (fast) {
        convert_x_q<<<(M / BM) * KSTEPS, 256, 0, stream>>>(X, Xq);            // 64*32
        convert_v_q<<<(NV / BN) * KSTEPS, 256, 0, stream>>>(Vg, invnorm, Vq); // 125*32
        dim3 grid((NV / BN) * (M / BM));    // 125*64 = 8000 blocks
        sim_i8_ring<<<grid, 512, 0, stream>>>(Xq, Vq, R, M);
    } else {
        dim3 gridf((NV / 128) * (M / 128)); // 16000 blocks
        sim_coarse_fallback<<<gridf, 256, 0, stream>>>(X, Vg, invnorm,
                                                       R, R + M, R + 2 * M);
    }

    rescue_finalize_kernel<<<M, 256, 0, stream>>>(X, Vg, R, M, NV, outx, outid);
}

// Round 20
// 1233.732 us; speedup vs baseline: 1.3174x; 1.0035x over previous
//
#include <hip/hip_runtime.h>
#include <hip/hip_bf16.h>

#define DIM 2048
#define BM 128
#define BN 256
#define BK 64
#define KSTEPS (DIM / BK)          // 32 K-tiles
#define A_TILE_BYTES (BM * BK)     // 8192 B
#define B_TILE_BYTES (BN * BK)     // 16384 B
#define NLEV 8                     // global top-8 cascade

typedef _Float16 f16x8 __attribute__((ext_vector_type(8)));
typedef float f32x4 __attribute__((ext_vector_type(4)));
typedef int i32x4 __attribute__((ext_vector_type(4)));
typedef unsigned long long u64;

#define INV_SX 27.6f               // X scale: clip at 4.60 sigma
#define INV_SVN 1150.0f            // normalized-V scale: clip at |vn|=0.1104

typedef const unsigned int __attribute__((address_space(1))) gu32;
typedef unsigned int __attribute__((address_space(3))) lu32;

__device__ __forceinline__ void gl_lds16(const void* g, void* l) {
    __builtin_amdgcn_global_load_lds((gu32*)g, (lu32*)l, 16, 0, 0);
}

// Monotone float->uint map; pack (val, col) so u64 max = (max val, first col on ties)
__device__ __forceinline__ u64 pack_key(float v, unsigned int col) {
    unsigned int b = __float_as_uint(v);
    b ^= (unsigned int)(((int)b >> 31)) | 0x80000000u;
    return ((u64)b << 32) | (u64)(~col);
}
// integer-dot key: monotone in dot, lowest col on ties
__device__ __forceinline__ u64 pack_key_i(int dot, unsigned int col) {
    unsigned int b = (unsigned int)dot ^ 0x80000000u;
    return ((u64)b << 32) | (u64)(~col);
}
__device__ __forceinline__ u64 umax64(u64 a, u64 b) { return a > b ? a : b; }
__device__ __forceinline__ u64 umin64(u64 a, u64 b) { return a < b ? a : b; }

// lock-free exact top-N cascade (order-independent => deterministic).
__device__ __forceinline__ void cascadeN(u64* Rrow, int stride, u64 k) {
    if (k <= Rrow[(NLEV - 1) * stride]) return;   // monotone prune (safe)
#pragma unroll
    for (int l = 0; l < NLEV; ++l) {
        u64 old = atomicMax(&Rrow[l * stride], k);
        k = umin64(k, old);
        if (!k) return;
    }
}
__device__ __forceinline__ void cascade3(u64* r1, u64* r2, u64* r3, u64 k) {
    u64 old = atomicMax(r1, k);
    k = umin64(k, old);
    if (k) {
        old = atomicMax(r2, k);
        k = umin64(k, old);
        if (k) atomicMax(r3, k);
    }
}

// tile image: 128B lines (row pairs of 64B), 8x16B slots, slot ^= line&7
// (byte-identical to the r6-r18 verified image)
__device__ __forceinline__ int toff(int row, int kg) {
    const int line = row >> 1;
    const int s8 = ((row & 1) << 2) | kg;
    return line * 128 + ((s8 ^ (line & 7)) << 4);   // byte offset
}

// old f16 swizzle (used by the 128^2 fallback kernel only)
__device__ __forceinline__ int swz(int row, int slot) {
    return row * 32 + (slot ^ ((row >> 1) & 3)) * 8;
}

__global__ void vocab_invnorm_kernel(const float* __restrict__ Vg,
                                     float* __restrict__ invnorm) {
    const int v = blockIdx.x;
    const int t = threadIdx.x;
    const float* row = Vg + (size_t)v * DIM;
    float4 f0 = *reinterpret_cast<const float4*>(row + t * 8);
    float4 f1 = *reinterpret_cast<const float4*>(row + t * 8 + 4);
    float s = f0.x*f0.x + f0.y*f0.y + f0.z*f0.z + f0.w*f0.w
            + f1.x*f1.x + f1.y*f1.y + f1.z*f1.z + f1.w*f1.w;
#pragma unroll
    for (int off = 32; off > 0; off >>= 1) s += __shfl_down(s, off);
    __shared__ float ls[4];
    const int lane = t & 63, w = t >> 6;
    if (lane == 0) ls[w] = s;
    __syncthreads();
    if (t == 0) {
        float tot = ls[0] + ls[1] + ls[2] + ls[3];
        invnorm[v] = 1.0f / fmaxf(sqrtf(tot), 1e-12f);
    }
}

__device__ __forceinline__ void q16pack(const float* xv, float s, int* out4) {
#pragma unroll
    for (int g = 0; g < 4; ++g) {
        int p = 0;
#pragma unroll
        for (int e = 0; e < 4; ++e) {
            int q = __float2int_rn(xv[g * 4 + e] * s);
            q = q > 127 ? 127 : (q < -127 ? -127 : q);
            p |= (q & 255) << (e * 8);
        }
        out4[g] = p;
    }
}

// X -> tiled i8, [128][64] tiles in the line/slot-swizzled image (fixed scale)
__global__ void convert_x_q(const float* __restrict__ X, signed char* __restrict__ Xq) {
    const int tile = blockIdx.x;          // mblk*32 + ks
    const int mblk = tile >> 5, ks = tile & 31;
    const float* src = X + (size_t)(mblk * BM) * DIM + ks * BK;
    signed char* dst = Xq + (size_t)tile * A_TILE_BYTES;
    const int t = threadIdx.x;
#pragma unroll
    for (int u = 0; u < 2; ++u) {
        const int c = t + u * 256;        // 0..511 chunk id (16 B each)
        const int line = c >> 3;
        const int s8 = (c & 7) ^ (line & 7);
        const int row = (line << 1) | (s8 >> 2);
        const int cs = s8 & 3;            // 16-elem slot
        const float* s = src + (size_t)row * DIM + cs * 16;
        float xv[16];
        *(float4*)(&xv[0])  = *(const float4*)(s);
        *(float4*)(&xv[4])  = *(const float4*)(s + 4);
        *(float4*)(&xv[8])  = *(const float4*)(s + 8);
        *(float4*)(&xv[12]) = *(const float4*)(s + 12);
        int q4[4];
        q16pack(xv, INV_SX, q4);
        *(int4*)(dst + c * 16) = make_int4(q4[0], q4[1], q4[2], q4[3]);
    }
}

// V -> tiled i8, [256][64] tiles (same image), normalized then fixed-scale
__global__ void convert_v_q(const float* __restrict__ Vg,
                            const float* __restrict__ invnorm,
                            signed char* __restrict__ Vq) {
    const int tile = blockIdx.x;          // nblk*32 + ks
    const int nblk = tile >> 5, ks = tile & 31;
    const float* src = Vg + (size_t)(nblk * BN) * DIM + ks * BK;
    signed char* dst = Vq + (size_t)tile * B_TILE_BYTES;
    const int t = threadIdx.x;
#pragma unroll
    for (int u = 0; u < 4; ++u) {
        const int c = t + u * 256;        // 0..1023
        const int line = c >> 3;
        const int s8 = (c & 7) ^ (line & 7);
        const int row = (line << 1) | (s8 >> 2);
        const int cs = s8 & 3;
        const float sc = invnorm[nblk * BN + row] * INV_SVN;
        const float* s = src + (size_t)row * DIM + cs * 16;
        float xv[16];
        *(float4*)(&xv[0])  = *(const float4*)(s);
        *(float4*)(&xv[4])  = *(const float4*)(s + 4);
        *(float4*)(&xv[8])  = *(const float4*)(s + 8);
        *(float4*)(&xv[12]) = *(const float4*)(s + 12);
        int q4[4];
        q16pack(xv, sc, q4);
        *(int4*)(dst + c * 16) = make_int4(q4[0], q4[1], q4[2], q4[3]);
    }
}

// 512 threads = 8 waves (2m x 4n), wave tile 64x64, block tile 128x256.
// r18 VERIFIED schedule: 4-slot A-ring with counted vmcnt(9) (order-robust)
// and raw s_barrier followed by sched_barrier(0) (rule-18 fence). DMA stays
// ~2 iterations in flight; never drained to 0 mid-loop. Only addition vs
// r18: s_setprio(1)/(0) around the MFMA cluster (T5; correctness-neutral).
__global__ __launch_bounds__(512, 4) void sim_i8_ring(
        const signed char* __restrict__ Xq, const signed char* __restrict__ Vq,
        u64* __restrict__ R, int M) {
    __shared__ alignas(16) signed char ldsA[4][A_TILE_BYTES];   // 32 KB

    const int tid = threadIdx.x;
    // XCD-chunked bijective swizzle: 8000 blocks = 8 x 1000; m-fastest in chunk
    const int flat = blockIdx.x;
    const int idx  = (flat & 7) * 1000 + (flat >> 3);
    const int mblk = idx & 63;           // M/128 = 64
    const int nblk = idx >> 6;           // NV/256 = 125

    const int lane = tid & 63;
    const int w  = tid >> 6;             // 0..7
    const int wm = w >> 2, wn = w & 3;   // 2x4 wave grid; wave tile 64x64
    const int lr = lane & 15;
    const int kg = lane >> 4;

    const signed char* Atiles = Xq + (size_t)mblk * KSTEPS * A_TILE_BYTES;
    const signed char* Btiles = Vq + (size_t)nblk * KSTEPS * B_TILE_BYTES;

    i32x4 acc[4][4] = {};

    int offA[4], offB[4];
#pragma unroll
    for (int i = 0; i < 4; ++i) offA[i] = toff(wm * 64 + i * 16 + lr, kg);
#pragma unroll
    for (int j = 0; j < 4; ++j) offB[j] = toff(wn * 64 + j * 16 + lr, kg);

    const int cA = tid * 16;             // A staging: 512 chunks of 16B, 1/thread

    // prologue: DMA A(0)->slot0, A(1)->slot1; B(0) frags -> regs; drain once
    gl_lds16(Atiles + cA,                &ldsA[0][cA]);
    gl_lds16(Atiles + A_TILE_BYTES + cA, &ldsA[1][cA]);
    i32x4 b0 = *(const i32x4*)(Btiles + offB[0]);
    i32x4 b1 = *(const i32x4*)(Btiles + offB[1]);
    i32x4 b2 = *(const i32x4*)(Btiles + offB[2]);
    i32x4 b3 = *(const i32x4*)(Btiles + offB[3]);
    asm volatile("s_waitcnt vmcnt(0)" ::: "memory");
    __builtin_amdgcn_s_barrier();
    __builtin_amdgcn_sched_barrier(0);

    for (int ks = 0; ks < KSTEPS; ++ks) {
        // issue B(ks+1) frags -> regs (clamped tail: harmless reload)
        const int nk = (ks + 1 < KSTEPS) ? (ks + 1) : (KSTEPS - 1);
        const signed char* bn = Btiles + (size_t)nk * B_TILE_BYTES;
        i32x4 nb0 = *(const i32x4*)(bn + offB[0]);
        i32x4 nb1 = *(const i32x4*)(bn + offB[1]);
        i32x4 nb2 = *(const i32x4*)(bn + offB[2]);
        i32x4 nb3 = *(const i32x4*)(bn + offB[3]);
        // issue DMA A(ks+2) -> slot (ks+2)&3 (clamped src; dead slot at tail, WAR-safe)
        const int ak = (ks + 2 < KSTEPS) ? (ks + 2) : (KSTEPS - 1);
        gl_lds16(Atiles + (size_t)ak * A_TILE_BYTES + cA, &ldsA[(ks + 2) & 3][cA]);
        // counted wait: 5 vmem ops/iter; vmcnt(9) retires 5ks-4 ops, which
        // covers iter ks-2's whole block (last index 5ks-6) for ANY intra-iter
        // order => DMA A(ks) landed. Barrier: slot ks&3 complete for ALL waves.
        asm volatile("s_waitcnt vmcnt(9)" ::: "memory");
        __builtin_amdgcn_s_barrier();
        __builtin_amdgcn_sched_barrier(0);   // rule-18 fence: no ds_read hoist

        const signed char* As = &ldsA[ks & 3][0];
        __builtin_amdgcn_s_setprio(1);
#pragma unroll
        for (int i = 0; i < 4; ++i) {
            i32x4 ahf = *(const i32x4*)(As + offA[i]);
            acc[i][0] = __builtin_amdgcn_mfma_i32_16x16x64_i8(ahf, b0, acc[i][0], 0, 0, 0);
            acc[i][1] = __builtin_amdgcn_mfma_i32_16x16x64_i8(ahf, b1, acc[i][1], 0, 0, 0);
            acc[i][2] = __builtin_amdgcn_mfma_i32_16x16x64_i8(ahf, b2, acc[i][2], 0, 0, 0);
            acc[i][3] = __builtin_amdgcn_mfma_i32_16x16x64_i8(ahf, b3, acc[i][3], 0, 0, 0);
        }
        __builtin_amdgcn_s_setprio(0);
        b0 = nb0; b1 = nb1; b2 = nb2; b3 = nb3;
    }

    // epilogue: per-row top-2 within wave cols -> global top-8 cascade
    const int m0 = mblk * BM, n0 = nblk * BN;
#pragma unroll
    for (int i = 0; i < 4; ++i) {
#pragma unroll
        for (int r = 0; r < 4; ++r) {
            u64 k[4];
#pragma unroll
            for (int j = 0; j < 4; ++j)
                k[j] = pack_key_i(acc[i][j][r],
                                  (unsigned int)(n0 + wn * 64 + j * 16 + lr));
            u64 m01 = umax64(k[0], k[1]), q01 = umin64(k[0], k[1]);
            u64 m23 = umax64(k[2], k[3]), q23 = umin64(k[2], k[3]);
            u64 a1k = umax64(m01, m23);
            u64 a2k = umax64(umin64(m01, m23), umax64(q01, q23));
#pragma unroll
            for (int mask = 1; mask < 16; mask <<= 1) {
                u64 o1 = __shfl_xor(a1k, mask);
                u64 o2 = __shfl_xor(a2k, mask);
                u64 t1 = umax64(a1k, o1);
                a2k = umax64(umin64(a1k, o1), umax64(a2k, o2));
                a1k = t1;
            }
            if (lr == 0) {
                const int row = m0 + wm * 64 + i * 16 + kg * 4 + r;
                cascadeN(&R[row], M, a1k);
                cascadeN(&R[row], M, a2k);
            }
        }
    }
}

// ---------------- fallback (verified round-3 path, 128^2 f16; used if ws too small) ----------------
__global__ __launch_bounds__(256) void sim_coarse_fallback(
        const float* __restrict__ X, const float* __restrict__ Vg,
        const float* __restrict__ invnorm,
        u64* __restrict__ R1, u64* __restrict__ R2, u64* __restrict__ R3) {
    __shared__ alignas(16) _Float16 Ah[128 * 32];
    __shared__ alignas(16) _Float16 Bh[128 * 32];
    const int tid = threadIdx.x;
    const int flat = blockIdx.x;
    const int idx  = (flat & 7) * 2000 + (flat >> 3);
    const int panel = idx / 3200;
    const int w_    = idx - panel * 3200;
    const int mblk  = w_ & 63;
    const int nblk  = panel * 50 + (w_ >> 6);
    const int m0 = mblk * 128, n0 = nblk * 128;
    const int lane = tid & 63;
    const int w  = tid >> 6;
    const int wm = w >> 1, wn = w & 1;
    const int lr = lane & 15;
    const int kg = lane >> 4;
    const int sr  = tid >> 2;
    const int skc = tid & 3;
    const float* Aptr0 = X  + (size_t)(m0 + sr)      * DIM + skc * 8;
    const float* Aptr1 = X  + (size_t)(m0 + 64 + sr) * DIM + skc * 8;
    const float* Bptr0 = Vg + (size_t)(n0 + sr)      * DIM + skc * 8;
    const float* Bptr1 = Vg + (size_t)(n0 + 64 + sr) * DIM + skc * 8;
    float4 ra[4], rb[4];
    ra[0] = *(const float4*)(Aptr0);     ra[1] = *(const float4*)(Aptr0 + 4);
    ra[2] = *(const float4*)(Aptr1);     ra[3] = *(const float4*)(Aptr1 + 4);
    rb[0] = *(const float4*)(Bptr0);     rb[1] = *(const float4*)(Bptr0 + 4);
    rb[2] = *(const float4*)(Bptr1);     rb[3] = *(const float4*)(Bptr1 + 4);
    f32x4 acc[4][4] = {};
    const int wA0 = swz(sr, skc), wA1 = swz(sr + 64, skc);
    for (int ks = 0; ks < 64; ++ks) {
        {
            f16x8 h; float xv[8];
            *(float4*)(&xv[0]) = ra[0]; *(float4*)(&xv[4]) = ra[1];
#pragma unroll
            for (int e = 0; e < 8; ++e) h[e] = (_Float16)xv[e];
            *(f16x8*)(&Ah[wA0]) = h;
            *(float4*)(&xv[0]) = ra[2]; *(float4*)(&xv[4]) = ra[3];
#pragma unroll
            for (int e = 0; e < 8; ++e) h[e] = (_Float16)xv[e];
            *(f16x8*)(&Ah[wA1]) = h;
            *(float4*)(&xv[0]) = rb[0]; *(float4*)(&xv[4]) = rb[1];
#pragma unroll
            for (int e = 0; e < 8; ++e) h[e] = (_Float16)xv[e];
            *(f16x8*)(&Bh[wA0]) = h;
            *(float4*)(&xv[0]) = rb[2]; *(float4*)(&xv[4]) = rb[3];
#pragma unroll
            for (int e = 0; e < 8; ++e) h[e] = (_Float16)xv[e];
            *(f16x8*)(&Bh[wA1]) = h;
        }
        __syncthreads();
        if (ks + 1 < 64) {
            const int ko = (ks + 1) * 32;
            ra[0] = *(const float4*)(Aptr0 + ko); ra[1] = *(const float4*)(Aptr0 + ko + 4);
            ra[2] = *(const float4*)(Aptr1 + ko); ra[3] = *(const float4*)(Aptr1 + ko + 4);
            rb[0] = *(const float4*)(Bptr0 + ko); rb[1] = *(const float4*)(Bptr0 + ko + 4);
            rb[2] = *(const float4*)(Bptr1 + ko); rb[3] = *(const float4*)(Bptr1 + ko + 4);
        }
        f16x8 bhf[4];
#pragma unroll
        for (int j = 0; j < 4; ++j)
            bhf[j] = *(const f16x8*)(&Bh[swz(wn * 64 + j * 16 + lr, kg)]);
#pragma unroll
        for (int i = 0; i < 4; ++i) {
            f16x8 ahf = *(const f16x8*)(&Ah[swz(wm * 64 + i * 16 + lr, kg)]);
#pragma unroll
            for (int j = 0; j < 4; ++j)
                acc[i][j] = __builtin_amdgcn_mfma_f32_16x16x32_f16(ahf, bhf[j], acc[i][j], 0, 0, 0);
        }
        __syncthreads();
    }
    float inv[4];
#pragma unroll
    for (int j = 0; j < 4; ++j) inv[j] = invnorm[n0 + wn * 64 + j * 16 + lr];
#pragma unroll
    for (int i = 0; i < 4; ++i) {
#pragma unroll
        for (int r = 0; r < 4; ++r) {
            u64 k[4];
#pragma unroll
            for (int j = 0; j < 4; ++j)
                k[j] = pack_key(acc[i][j][r] * inv[j],
                                (unsigned int)(n0 + wn * 64 + j * 16 + lr));
            u64 m01 = umax64(k[0], k[1]), n01 = umin64(k[0], k[1]);
            u64 m23 = umax64(k[2], k[3]), n23 = umin64(k[2], k[3]);
            u64 a1 = umax64(m01, m23);
            u64 a2 = umax64(umin64(m01, m23), umax64(n01, n23));
#pragma unroll
            for (int mask = 1; mask < 16; mask <<= 1) {
                u64 b1 = __shfl_xor(a1, mask);
                u64 b2 = __shfl_xor(a2, mask);
                u64 t1 = umax64(a1, b1);
                a2 = umax64(umin64(a1, b1), umax64(a2, b2));
                a1 = t1;
            }
            if (lr == 0) {
                const int row = m0 + wm * 64 + i * 16 + kg * 4 + r;
                cascade3(&R1[row], &R2[row], &R3[row], a1);
                cascade3(&R1[row], &R2[row], &R3[row], a2);
            }
        }
    }
}

// block-wide sum reduction; returns total to ALL threads
__device__ __forceinline__ float block_sum(float v, float* sbuf, int t) {
#pragma unroll
    for (int off = 32; off > 0; off >>= 1) v += __shfl_down(v, off);
    const int lane = t & 63, w = t >> 6;
    __syncthreads();
    if (lane == 0) sbuf[w] = v;
    __syncthreads();
    return sbuf[0] + sbuf[1] + sbuf[2] + sbuf[3];
}

__global__ void rescue_finalize_kernel(const float* __restrict__ X,
                                       const float* __restrict__ Vg,
                                       const u64* __restrict__ R, int M, int NV,
                                       float* __restrict__ outx,
                                       float* __restrict__ outid) {
    const int row = blockIdx.x;
    const int t = threadIdx.x;
    __shared__ float sbuf[4];

    int cand[NLEV];
#pragma unroll
    for (int c = 0; c < NLEV; ++c) {
        unsigned int id = ~(unsigned int)(R[c * M + row] & 0xFFFFFFFFull);
        cand[c] = (id < (unsigned int)NV) ? (int)id : 0;
    }

    const float* x = X + (size_t)row * DIM;
    float4 x0 = *reinterpret_cast<const float4*>(x + t * 8);
    float4 x1 = *reinterpret_cast<const float4*>(x + t * 8 + 4);
    float xxp = x0.x*x0.x + x0.y*x0.y + x0.z*x0.z + x0.w*x0.w
              + x1.x*x1.x + x1.y*x1.y + x1.z*x1.z + x1.w*x1.w;
    const float xx = block_sum(xxp, sbuf, t);
    const float xn = fmaxf(sqrtf(xx), 1e-12f);

    u64 bestkey = 0ull;
    int bestid = cand[0];
    float bestsa = 0.f;
#pragma unroll
    for (int c = 0; c < NLEV; ++c) {
        const float* v = Vg + (size_t)cand[c] * DIM;
        float4 v0 = *reinterpret_cast<const float4*>(v + t * 8);
        float4 v1 = *reinterpret_cast<const float4*>(v + t * 8 + 4);
        float dp = x0.x*v0.x + x0.y*v0.y + x0.z*v0.z + x0.w*v0.w
                 + x1.x*v1.x + x1.y*v1.y + x1.z*v1.z + x1.w*v1.w;
        float vp = v0.x*v0.x + v0.y*v0.y + v0.z*v0.z + v0.w*v0.w
                 + v1.x*v1.x + v1.y*v1.y + v1.z*v1.z + v1.w*v1.w;
        const float dot = block_sum(dp, sbuf, t);
        const float vv  = block_sum(vp, sbuf, t);
        const float s = dot / (xn * fmaxf(sqrtf(vv), 1e-12f));
        u64 key = pack_key(s, (unsigned int)cand[c]);
        if (key > bestkey) { bestkey = key; bestid = cand[c]; bestsa = vv; }
    }

    const float* a = Vg + (size_t)bestid * DIM;
    float4 a0 = *reinterpret_cast<const float4*>(a + t * 8);
    float4 a1 = *reinterpret_cast<const float4*>(a + t * 8 + 4);
    float4 d0 = make_float4(x0.x-a0.x, x0.y-a0.y, x0.z-a0.z, x0.w-a0.w);
    float4 d1 = make_float4(x1.x-a1.x, x1.y-a1.y, x1.z-a1.z, x1.w-a1.w);
    float sop = d0.x*d0.x + d0.y*d0.y + d0.z*d0.z + d0.w*d0.w
              + d1.x*d1.x + d1.y*d1.y + d1.z*d1.z + d1.w*d1.w;
    const float so = block_sum(sop, sbuf, t);
    const float scale = fminf(0.1f * sqrtf(bestsa) / (sqrtf(so) + 1e-8f), 1.0f);

    float4 o0 = make_float4(a0.x + d0.x*scale, a0.y + d0.y*scale,
                            a0.z + d0.z*scale, a0.w + d0.w*scale);
    float4 o1 = make_float4(a1.x + d1.x*scale, a1.y + d1.y*scale,
                            a1.z + d1.z*scale, a1.w + d1.w*scale);
    float* o = outx + (size_t)row * DIM + t * 8;
    *reinterpret_cast<float4*>(o)     = o0;
    *reinterpret_cast<float4*>(o + 4) = o1;
    if (t == 0) outid[row] = (float)bestid;
}

extern "C" void kernel_launch(void* const* d_in, const int* in_sizes, int n_in,
                              void* d_out, int out_size, void* d_ws, size_t ws_size,
                              hipStream_t stream) {
    const float* X  = (const float*)d_in[0];
    const float* Vg = (const float*)d_in[1];
    const int M  = in_sizes[0] / DIM;   // 8192
    const int NV = in_sizes[1] / DIM;   // 32000

    char* ws = (char*)d_ws;
    u64* R = (u64*)ws;                                   // NLEV levels x M
    size_t off = (size_t)NLEV * M * sizeof(u64);         // 512 KB
    float* invnorm = (float*)(ws + off);
    off += ((size_t)NV * sizeof(float) + 255) & ~255ull; // 128 KB
    signed char* Xq = (signed char*)(ws + off);
    off += (size_t)M * DIM;                              // 16 MB
    signed char* Vq = (signed char*)(ws + off);
    off += (size_t)NV * DIM;                             // 64 MB
    const bool fast = (ws_size >= off);

    float* outx  = (float*)d_out;
    float* outid = outx + (size_t)M * DIM;

    hipMemsetAsync(R, 0, (size_t)NLEV * M * sizeof(u64), stream);
    vocab_invnorm_kernel<<<NV, 256, 0, stream>>>(Vg, invnorm);

    if (fast) {
        convert_x_q<<<(M / BM) * KSTEPS, 256, 0, stream>>>(X, Xq);            // 64*32
        convert_v_q<<<(NV / BN) * KSTEPS, 256, 0, stream>>>(Vg, invnorm, Vq); // 125*32
        dim3 grid((NV / BN) * (M / BM));    // 125*64 = 8000 blocks
        sim_i8_ring<<<grid, 512, 0, stream>>>(Xq, Vq, R, M);
    } else {
        dim3 gridf((NV / 128) * (M / 128)); // 16000 blocks
        sim_coarse_fallback<<<gridf, 256, 0, stream>>>(X, Vg, invnorm,
                                                       R, R + M, R + 2 * M);
    }

    rescue_finalize_kernel<<<M, 256, 0, stream>>>(X, Vg, R, M, NV, outx, outid);
}